// Round 9
// baseline (217.170 us; speedup 1.0000x reference)
//
#include <hip/hip_runtime.h>
#include <stdint.h>
#include <stddef.h>

#define BB 64
#define DIN 1024
#define DD 768
#define CC 1000
#define EPSA 0.1f
#define NSIM 3

typedef short  s16x8 __attribute__((ext_vector_type(8)));
typedef float  f32x4 __attribute__((ext_vector_type(4)));

static __device__ __forceinline__ unsigned short f2bf_rne(float x) {
  unsigned u = __float_as_uint(x);
  return (unsigned short)((u + 0x7FFFu + ((u >> 16) & 1u)) >> 16);
}

// ---------------------------------------------------------------- pack W (bf16 MFMA frag order) + An2, fused
// blocks 0..383: Bp[nt][ks][lane][reg]: row = nt*16+(lane&15), k = ks*32+(lane>>4)*8+reg
// blocks 384..633: An2[j] = ||anchors_j||^2
__global__ __launch_bounds__(256) void packAn2_kernel(const float* __restrict__ W_fc,
                                                      const float* __restrict__ anchors,
                                                      short* __restrict__ Bp,
                                                      float* __restrict__ An2) {
  int blk = blockIdx.x;
  if (blk < 384) {
    int gid = blk * 256 + threadIdx.x;     // 64*24*64 = 98304
    if (gid >= 64 * 24 * 64) return;
    int lane = gid & 63;
    int ks   = (gid >> 6) % 24;
    int nt   = gid / (64 * 24);
    int c  = nt * 16 + (lane & 15);
    int k0 = ks * 32 + (lane >> 4) * 8;
    s16x8 vh;
    #pragma unroll
    for (int r = 0; r < 8; ++r) {
      float w = (c < CC) ? W_fc[(size_t)c * DD + k0 + r] : 0.0f;
      vh[r] = (short)f2bf_rne(w);
    }
    ((s16x8*)Bp)[gid] = vh;
  } else {
    int w = threadIdx.x >> 6, lane = threadIdx.x & 63;
    int j = (blk - 384) * 4 + w;           // < 1000
    const float4* ar = (const float4*)(anchors + (size_t)j * DD);
    float an = 0.f;
    for (int k4 = lane; k4 < DD / 4; k4 += 64) {
      float4 a = ar[k4];
      an += a.x*a.x + a.y*a.y + a.z*a.z + a.w*a.w;
    }
    #pragma unroll
    for (int o = 1; o < 64; o <<= 1) an += __shfl_xor(an, o);
    if (lane == 0) An2[j] = an;
  }
}

// ---------------------------------------------------------------- V = W_fc @ W_fc^T  [1024,1024] (bf16 MFMA, fp32 out)
__global__ __launch_bounds__(256) void V_kernel(const short* __restrict__ Bp,
                                                float* __restrict__ V) {
  const int tid = threadIdx.x;
  const int w = tid >> 6, lane = tid & 63;
  const int rnt = blockIdx.x * 4 + w;       // rows rnt*16..+15
  const int cb  = blockIdx.y;               // cols cb*64..+63
  const s16x8* BH = (const s16x8*)Bp;
  f32x4 acc[4] = {};
  for (int ks = 0; ks < 24; ++ks) {
    s16x8 a = BH[(rnt * 24 + ks) * 64 + lane];
    #pragma unroll
    for (int nf = 0; nf < 4; ++nf) {
      s16x8 bf = BH[((cb * 4 + nf) * 24 + ks) * 64 + lane];
      acc[nf] = __builtin_amdgcn_mfma_f32_16x16x32_bf16(a, bf, acc[nf], 0, 0, 0);
    }
  }
  const int r0 = rnt * 16 + (lane >> 4) * 4;   // C/D: row=(lane>>4)*4+reg, col=lane&15 [m89]
  const int c0 = cb * 64 + (lane & 15);
  #pragma unroll
  for (int nf = 0; nf < 4; ++nf)
    #pragma unroll
    for (int rr = 0; rr < 4; ++rr)
      V[(size_t)(r0 + rr) * 1024 + c0 + nf * 16] = acc[nf][rr];
}

// ---------------------------------------------------------------- emb = x @ W_emb^T + b_emb  [64,768]; 4 lanes per d
__global__ __launch_bounds__(256) void emb_kernel(const float* __restrict__ x,
                                                  const float* __restrict__ W_emb,
                                                  const float* __restrict__ b_emb,
                                                  float* __restrict__ emb) {
  int b = blockIdx.x;
  int y = blockIdx.y;                        // 0..11
  int dl = threadIdx.x >> 2, kq = threadIdx.x & 3;
  int d = y * 64 + dl;                       // < 768
  __shared__ __attribute__((aligned(16))) float xs[DIN];
  for (int k = threadIdx.x; k < DIN; k += 256) xs[k] = x[b * DIN + k];
  __syncthreads();
  const float4* xs4 = (const float4*)xs;
  const float4* wr = (const float4*)(W_emb + (size_t)d * DIN);
  float acc = 0.f;
  #pragma unroll 8
  for (int i = 0; i < 64; ++i) {             // quarter = 1024/4/4 float4
    int k4 = kq * 64 + i;
    float4 w = wr[k4];
    float4 xv = xs4[k4];
    acc += xv.x*w.x + xv.y*w.y + xv.z*w.z + xv.w*w.w;
  }
  acc += __shfl_xor(acc, 1);
  acc += __shfl_xor(acc, 2);
  if (kq == 0) emb[b * DD + d] = acc + b_emb[d];
}

// ---------------------------------------------------------------- logits + AE + En2 (fused; 4 lanes per c)
__global__ __launch_bounds__(256) void logitsAE_kernel(const float* __restrict__ emb,
                                                       const float* __restrict__ W_fc,
                                                       const float* __restrict__ anchors,
                                                       const float* __restrict__ b_fc,
                                                       float* __restrict__ logits,
                                                       float* __restrict__ AE,
                                                       float* __restrict__ En2) {
  int b = blockIdx.x;
  int y = blockIdx.y;                        // 0..15
  int cl = threadIdx.x >> 2, kq = threadIdx.x & 3;
  int c = y * 64 + cl;                       // < 1024, guarded
  __shared__ __attribute__((aligned(16))) float es[DD];
  for (int k = threadIdx.x; k < DD; k += 256) es[k] = emb[b * DD + k];
  __syncthreads();

  if (y == 0) {   // En2[b] (block-uniform branch)
    float pe = 0.f;
    for (int k = threadIdx.x; k < DD; k += 256) pe += es[k] * es[k];
    #pragma unroll
    for (int o = 1; o < 64; o <<= 1) pe += __shfl_xor(pe, o);
    __shared__ float se[4];
    if ((threadIdx.x & 63) == 0) se[threadIdx.x >> 6] = pe;
    __syncthreads();
    if (threadIdx.x == 0) En2[b] = se[0] + se[1] + se[2] + se[3];
  }

  if (c >= CC) return;
  const float4* es4 = (const float4*)es;
  const float4* wr = (const float4*)(W_fc + (size_t)c * DD);
  const float4* ar = (const float4*)(anchors + (size_t)c * DD);
  float accL = 0.f, accA = 0.f;
  #pragma unroll 8
  for (int i = 0; i < 48; ++i) {             // quarter = 768/4/4 float4
    int k4 = kq * 48 + i;
    float4 w = wr[k4];
    float4 a = ar[k4];
    float4 e = es4[k4];
    accL += e.x*w.x + e.y*w.y + e.z*w.z + e.w*w.w;
    accA += e.x*a.x + e.y*a.y + e.z*a.z + e.w*a.w;
  }
  accL += __shfl_xor(accL, 1); accL += __shfl_xor(accL, 2);
  accA += __shfl_xor(accA, 1); accA += __shfl_xor(accA, 2);
  if (kq == 0) {
    logits[b * CC + c] = accL + b_fc[c];
    AE[b * CC + c]     = accA;
  }
}

// ---------------------------------------------------------------- softmax + argmax(logits)
__global__ __launch_bounds__(256) void softmax_kernel(const float* __restrict__ logits,
                                                      float* __restrict__ p,
                                                      int* __restrict__ pred) {
  int b = blockIdx.x, t = threadIdx.x;
  __shared__ float smax[256];
  __shared__ int   sidx[256];
  __shared__ float ssum[256];
  float m = -3.402823466e38f; int mi = 0;
  for (int c = t; c < CC; c += 256) {
    float v = logits[b * CC + c];
    if (v > m) { m = v; mi = c; }
  }
  smax[t] = m; sidx[t] = mi;
  __syncthreads();
  for (int o = 128; o > 0; o >>= 1) {
    if (t < o) {
      float v2 = smax[t + o]; int i2 = sidx[t + o];
      if (v2 > smax[t] || (v2 == smax[t] && i2 < sidx[t])) { smax[t] = v2; sidx[t] = i2; }
    }
    __syncthreads();
  }
  float M = smax[0];
  if (t == 0) pred[b] = sidx[0];
  float sum = 0.f;
  for (int c = t; c < CC; c += 256) sum += expf(logits[b * CC + c] - M);
  ssum[t] = sum;
  __syncthreads();
  for (int o = 128; o > 0; o >>= 1) {
    if (t < o) ssum[t] += ssum[t + o];
    __syncthreads();
  }
  float S = ssum[0];
  for (int c = t; c < CC; c += 256) p[b * CC + c] = expf(logits[b * CC + c] - M) / S;
}

// ---------------------------------------------------------------- u[b,c] = sum_j p[b,j] * V[c,j]; 4 lanes per c
__global__ __launch_bounds__(256) void u_kernel(const float* __restrict__ p,
                                                const float* __restrict__ V,
                                                float* __restrict__ u) {
  int b = blockIdx.x;
  int y = blockIdx.y;                        // 0..15
  int cl = threadIdx.x >> 2, jq = threadIdx.x & 3;
  int c = y * 64 + cl;
  __shared__ __attribute__((aligned(16))) float4 ps4[256];
  if (threadIdx.x < 250) ps4[threadIdx.x] = ((const float4*)(p + b * CC))[threadIdx.x];
  else ps4[threadIdx.x] = float4{0.f, 0.f, 0.f, 0.f};
  __syncthreads();
  if (c >= CC) return;
  const float4* Vr = (const float4*)(V + (size_t)c * 1024);
  float acc = 0.f;
  #pragma unroll 7
  for (int i = 0; i < 63; ++i) {             // quarter = ceil(250/4)
    int j4 = jq * 63 + i;
    if (j4 < 250) {
      float4 v = Vr[j4];
      float4 pp = ps4[j4];
      acc += pp.x*v.x + pp.y*v.y + pp.z*v.z + pp.w*v.w;
    }
  }
  acc += __shfl_xor(acc, 1);
  acc += __shfl_xor(acc, 2);
  if (jq == 0) u[b * CC + c] = acc;
}

// ---------------------------------------------------------------- scan: per (b,j) argmax_c of logits[c] + s_j*(u[c] - V[j,c])
// s_j from norm algebra; Gn2 computed block-locally as p.u; Vd[j] = V[j,j].
__global__ __launch_bounds__(256) void scan_kernel(const float* __restrict__ logits,
                                                   const float* __restrict__ u,
                                                   const float* __restrict__ p,
                                                   const float* __restrict__ AE,
                                                   const float* __restrict__ An2,
                                                   const float* __restrict__ En2,
                                                   const float* __restrict__ V,
                                                   int* __restrict__ pm) {
  const int b = blockIdx.x, jb = blockIdx.y;   // jb < 32
  const int tid = threadIdx.x, w = tid >> 6, lane = tid & 63;
  __shared__ __attribute__((aligned(16))) float4 Ls4[256], Us4[256];
  __shared__ float se[4];
  __shared__ float sGn2;
  const float4* Lg = (const float4*)(logits + b * CC);
  const float4* Ug = (const float4*)(u + b * CC);
  float part = 0.f;
  if (tid < 250) {
    float4 l4 = Lg[tid], u4 = Ug[tid];
    float4 p4 = ((const float4*)(p + b * CC))[tid];
    Ls4[tid] = l4; Us4[tid] = u4;
    part = p4.x*u4.x + p4.y*u4.y + p4.z*u4.z + p4.w*u4.w;
  } else {
    Ls4[tid] = float4{0.f,0.f,0.f,0.f};
    Us4[tid] = float4{0.f,0.f,0.f,0.f};
  }
  #pragma unroll
  for (int o = 1; o < 64; o <<= 1) part += __shfl_xor(part, o);
  if (lane == 0) se[w] = part;
  __syncthreads();
  if (tid == 0) sGn2 = se[0] + se[1] + se[2] + se[3];
  __syncthreads();

  const float en2 = En2[b], gn2b = sGn2;
  const float* Usf = (const float*)Us4;
  for (int jj = 0; jj < 8; ++jj) {
    int j = jb * 32 + w * 8 + jj;
    if (j >= CC) break;                         // uniform per wave
    float zn2 = An2[j] - 2.0f * AE[b * CC + j] + en2;
    float gn2 = gn2b - 2.0f * Usf[j] + V[(size_t)j * 1024 + j];
    float sj = (EPSA * sqrtf(zn2)) / sqrtf(gn2);
    float best = -3.402823466e38f; int bi = 0;
    const float4* Vr = (const float4*)(V + (size_t)j * 1024);
    #pragma unroll
    for (int it = 0; it < 4; ++it) {
      int idx = it * 64 + lane;
      int c0 = idx * 4;
      float4 vv = Vr[idx];
      float4 l4 = Ls4[idx];
      float4 u4 = Us4[idx];
      float vals[4] = { l4.x + sj * (u4.x - vv.x),
                        l4.y + sj * (u4.y - vv.y),
                        l4.z + sj * (u4.z - vv.z),
                        l4.w + sj * (u4.w - vv.w) };
      #pragma unroll
      for (int comp = 0; comp < 4; ++comp) {
        int c = c0 + comp;
        if (c < CC && vals[comp] > best) { best = vals[comp]; bi = c; }
      }
    }
    #pragma unroll
    for (int o = 1; o < 64; o <<= 1) {
      float ov = __shfl_xor(best, o);
      int   oi = __shfl_xor(bi, o);
      if (ov > best || (ov == best && oi < bi)) { best = ov; bi = oi; }
    }
    if (lane == 0) pm[b * CC + j] = bi;
  }
}

// ---------------------------------------------------------------- counts + all(counts < 3)
__global__ __launch_bounds__(256) void counts_kernel(const int* __restrict__ pm,
                                                     const int* __restrict__ pred,
                                                     float* __restrict__ out) {
  int b = blockIdx.x, t = threadIdx.x;
  __shared__ int cnt[CC];
  __shared__ int bad;
  for (int c = t; c < CC; c += 256) cnt[c] = 0;
  if (t == 0) bad = 0;
  __syncthreads();
  if (t == 0) atomicAdd(&cnt[pred[b]], 1);
  for (int j = t; j < CC; j += 256) atomicAdd(&cnt[pm[b * CC + j]], 1);
  __syncthreads();
  for (int c = t; c < CC; c += 256) if (cnt[c] >= NSIM) bad = 1;
  __syncthreads();
  if (t == 0) out[b] = bad ? 0.0f : 1.0f;
}

// ---------------------------------------------------------------- launch
extern "C" void kernel_launch(void* const* d_in, const int* in_sizes, int n_in,
                              void* d_out, int out_size, void* d_ws, size_t ws_size,
                              hipStream_t stream) {
  const float* x       = (const float*)d_in[0];
  const float* W_emb   = (const float*)d_in[1];
  const float* b_emb   = (const float*)d_in[2];
  const float* W_fc    = (const float*)d_in[3];
  const float* b_fc    = (const float*)d_in[4];
  const float* anchors = (const float*)d_in[5];
  float* out = (float*)d_out;

  // workspace carve (~7.0 MB), all 16B-aligned
  float* emb    = (float*)d_ws;               // 64*768
  float* logits = emb + BB * DD;              // 64*1000
  float* p      = logits + BB * CC;           // 64*1000
  float* u      = p + BB * CC;                // 64*1000
  float* AE     = u + BB * CC;                // 64*1000
  float* An2    = AE + BB * CC;               // 1024
  float* En2    = An2 + 1024;                 // 64
  int*   pred   = (int*)(En2 + 64);           // 64
  int*   pm     = pred + 64;                  // 64*1000
  short* Bp     = (short*)(pm + BB * CC);     // 98304*8 bf16 bits (1.57 MB)
  float* V      = (float*)(Bp + 64 * 24 * 64 * 8);  // 1024*1024 f32 (4 MB)

  hipLaunchKernelGGL(packAn2_kernel, dim3(634), dim3(256), 0, stream, W_fc, anchors, Bp, An2);
  hipLaunchKernelGGL(V_kernel,       dim3(16, 16), dim3(256), 0, stream, Bp, V);
  hipLaunchKernelGGL(emb_kernel,     dim3(BB, 12), dim3(256), 0, stream, x, W_emb, b_emb, emb);
  hipLaunchKernelGGL(logitsAE_kernel,dim3(BB, 16), dim3(256), 0, stream,
                     emb, W_fc, anchors, b_fc, logits, AE, En2);
  hipLaunchKernelGGL(softmax_kernel, dim3(BB),    dim3(256), 0, stream, logits, p, pred);
  hipLaunchKernelGGL(u_kernel,       dim3(BB, 16), dim3(256), 0, stream, p, V, u);
  hipLaunchKernelGGL(scan_kernel,    dim3(BB, 32), dim3(256), 0, stream,
                     logits, u, p, AE, An2, En2, V, pm);
  hipLaunchKernelGGL(counts_kernel,  dim3(BB), dim3(256), 0, stream, pm, pred, out);
}

// Round 10
// 201.585 us; speedup vs baseline: 1.0773x; 1.0773x over previous
//
#include <hip/hip_runtime.h>
#include <stdint.h>
#include <stddef.h>

#define BB 64
#define DIN 1024
#define DD 768
#define CC 1000
#define EPSA 0.1f
#define NSIM 3

typedef short  s16x8 __attribute__((ext_vector_type(8)));
typedef float  f32x4 __attribute__((ext_vector_type(4)));

static __device__ __forceinline__ unsigned short f2bf_rne(float x) {
  unsigned u = __float_as_uint(x);
  return (unsigned short)((u + 0x7FFFu + ((u >> 16) & 1u)) >> 16);
}

// ---------------------------------------------------------------- pack W_fc (bf16 MFMA frag order) + An2, fused
__global__ __launch_bounds__(256) void packAn2_kernel(const float* __restrict__ W_fc,
                                                      const float* __restrict__ anchors,
                                                      short* __restrict__ Bp,
                                                      float* __restrict__ An2) {
  int blk = blockIdx.x;
  if (blk < 384) {
    int gid = blk * 256 + threadIdx.x;     // 64*24*64 = 98304
    if (gid >= 64 * 24 * 64) return;
    int lane = gid & 63;
    int ks   = (gid >> 6) % 24;
    int nt   = gid / (64 * 24);
    int c  = nt * 16 + (lane & 15);
    int k0 = ks * 32 + (lane >> 4) * 8;
    s16x8 vh;
    #pragma unroll
    for (int r = 0; r < 8; ++r) {
      float w = (c < CC) ? W_fc[(size_t)c * DD + k0 + r] : 0.0f;
      vh[r] = (short)f2bf_rne(w);
    }
    ((s16x8*)Bp)[gid] = vh;
  } else {
    int w = threadIdx.x >> 6, lane = threadIdx.x & 63;
    int j = (blk - 384) * 4 + w;           // < 1000
    const float4* ar = (const float4*)(anchors + (size_t)j * DD);
    float an = 0.f;
    for (int k4 = lane; k4 < DD / 4; k4 += 64) {
      float4 a = ar[k4];
      an += a.x*a.x + a.y*a.y + a.z*a.z + a.w*a.w;
    }
    #pragma unroll
    for (int o = 1; o < 64; o <<= 1) an += __shfl_xor(an, o);
    if (lane == 0) An2[j] = an;
  }
}

// ---------------------------------------------------------------- V = W_fc @ W_fc^T  [1024,1024] (bf16 MFMA, fp32 out)
__global__ __launch_bounds__(256) void V_kernel(const short* __restrict__ Bp,
                                                float* __restrict__ V) {
  const int tid = threadIdx.x;
  const int w = tid >> 6, lane = tid & 63;
  const int rnt = blockIdx.x * 4 + w;       // rows rnt*16..+15
  const int cb  = blockIdx.y;               // cols cb*64..+63
  const s16x8* BH = (const s16x8*)Bp;
  f32x4 acc[4] = {};
  for (int ks = 0; ks < 24; ++ks) {
    s16x8 a = BH[(rnt * 24 + ks) * 64 + lane];
    #pragma unroll
    for (int nf = 0; nf < 4; ++nf) {
      s16x8 bf = BH[((cb * 4 + nf) * 24 + ks) * 64 + lane];
      acc[nf] = __builtin_amdgcn_mfma_f32_16x16x32_bf16(a, bf, acc[nf], 0, 0, 0);
    }
  }
  const int r0 = rnt * 16 + (lane >> 4) * 4;   // C/D: row=(lane>>4)*4+reg, col=lane&15 [m89]
  const int c0 = cb * 64 + (lane & 15);
  #pragma unroll
  for (int nf = 0; nf < 4; ++nf)
    #pragma unroll
    for (int rr = 0; rr < 4; ++rr)
      V[(size_t)(r0 + rr) * 1024 + c0 + nf * 16] = acc[nf][rr];
}

// ---------------------------------------------------------------- emb = x @ W_emb^T + b_emb  [64,768]
// b-tile 16 staged flat in LDS; thread: 1 d column x 4 b rows; wave = b-subgroup (LDS broadcast).
__global__ __launch_bounds__(256) void emb_kernel(const float* __restrict__ x,
                                                  const float* __restrict__ W_emb,
                                                  const float* __restrict__ b_emb,
                                                  float* __restrict__ emb) {
  const int bt = blockIdx.x;                 // 4
  const int dt = blockIdx.y;                 // 12
  const int tid = threadIdx.x;
  const int d = dt * 64 + (tid & 63);
  const int bq = tid >> 6;                   // wave id 0..3
  __shared__ __attribute__((aligned(16))) float xs[16 * DIN];   // 64KB
  for (int i = tid * 4; i < 16 * DIN; i += 1024)
    *(float4*)&xs[i] = *(const float4*)&x[(size_t)(bt * 16) * DIN + i];
  __syncthreads();
  const float4* wr = (const float4*)(W_emb + (size_t)d * DIN);
  float acc[4] = {};
  #pragma unroll 8
  for (int k4 = 0; k4 < DIN / 4; ++k4) {
    float4 w = wr[k4];
    #pragma unroll
    for (int i = 0; i < 4; ++i) {
      const float4 xv = *(const float4*)&xs[(bq * 4 + i) * DIN + k4 * 4];
      acc[i] += xv.x*w.x + xv.y*w.y + xv.z*w.z + xv.w*w.w;
    }
  }
  const float be = b_emb[d];
  #pragma unroll
  for (int i = 0; i < 4; ++i)
    emb[(size_t)(bt * 16 + bq * 4 + i) * DD + d] = acc[i] + be;
}

// ---------------------------------------------------------------- logits + AE  (b-tile 16; thread: 1 c x 4 b, 2 streams)
__global__ __launch_bounds__(256) void logitsAE_kernel(const float* __restrict__ emb,
                                                       const float* __restrict__ W_fc,
                                                       const float* __restrict__ anchors,
                                                       const float* __restrict__ b_fc,
                                                       float* __restrict__ logits,
                                                       float* __restrict__ AE) {
  const int bt = blockIdx.x;                 // 4
  const int ct = blockIdx.y;                 // 16
  const int tid = threadIdx.x;
  const int c = ct * 64 + (tid & 63);
  const int cr = (c < CC) ? c : (CC - 1);
  const int bq = tid >> 6;
  __shared__ __attribute__((aligned(16))) float es[16 * DD];    // 48KB
  for (int i = tid * 4; i < 16 * DD; i += 1024)
    *(float4*)&es[i] = *(const float4*)&emb[(size_t)(bt * 16) * DD + i];
  __syncthreads();
  const float4* wr = (const float4*)(W_fc + (size_t)cr * DD);
  const float4* ar = (const float4*)(anchors + (size_t)cr * DD);
  float accL[4] = {}, accA[4] = {};
  #pragma unroll 8
  for (int k4 = 0; k4 < DD / 4; ++k4) {
    float4 w = wr[k4];
    float4 a = ar[k4];
    #pragma unroll
    for (int i = 0; i < 4; ++i) {
      const float4 e = *(const float4*)&es[(bq * 4 + i) * DD + k4 * 4];
      accL[i] += e.x*w.x + e.y*w.y + e.z*w.z + e.w*w.w;
      accA[i] += e.x*a.x + e.y*a.y + e.z*a.z + e.w*a.w;
    }
  }
  if (c < CC) {
    const float bf = b_fc[c];
    #pragma unroll
    for (int i = 0; i < 4; ++i) {
      int b = bt * 16 + bq * 4 + i;
      logits[b * CC + c] = accL[i] + bf;
      AE[b * CC + c]     = accA[i];
    }
  }
}

// ---------------------------------------------------------------- softmax + argmax(logits) + En2
__global__ __launch_bounds__(256) void softmax_kernel(const float* __restrict__ logits,
                                                      const float* __restrict__ emb,
                                                      float* __restrict__ p,
                                                      int* __restrict__ pred,
                                                      float* __restrict__ En2) {
  int b = blockIdx.x, t = threadIdx.x;
  __shared__ float smax[256];
  __shared__ int   sidx[256];
  __shared__ float ssum[256];
  // En2[b]
  {
    float pe = 0.f;
    for (int k = t; k < DD; k += 256) { float e = emb[b * DD + k]; pe += e * e; }
    #pragma unroll
    for (int o = 1; o < 64; o <<= 1) pe += __shfl_xor(pe, o);
    __shared__ float se[4];
    if ((t & 63) == 0) se[t >> 6] = pe;
    __syncthreads();
    if (t == 0) En2[b] = se[0] + se[1] + se[2] + se[3];
  }
  float m = -3.402823466e38f; int mi = 0;
  for (int c = t; c < CC; c += 256) {
    float v = logits[b * CC + c];
    if (v > m) { m = v; mi = c; }
  }
  smax[t] = m; sidx[t] = mi;
  __syncthreads();
  for (int o = 128; o > 0; o >>= 1) {
    if (t < o) {
      float v2 = smax[t + o]; int i2 = sidx[t + o];
      if (v2 > smax[t] || (v2 == smax[t] && i2 < sidx[t])) { smax[t] = v2; sidx[t] = i2; }
    }
    __syncthreads();
  }
  float M = smax[0];
  if (t == 0) pred[b] = sidx[0];
  float sum = 0.f;
  for (int c = t; c < CC; c += 256) sum += expf(logits[b * CC + c] - M);
  ssum[t] = sum;
  __syncthreads();
  for (int o = 128; o > 0; o >>= 1) {
    if (t < o) ssum[t] += ssum[t + o];
    __syncthreads();
  }
  float S = ssum[0];
  for (int c = t; c < CC; c += 256) p[b * CC + c] = expf(logits[b * CC + c] - M) / S;
}

// ---------------------------------------------------------------- u[b,c] = sum_j p[b,j] * V[c,j]  (b-tile 16)
__global__ __launch_bounds__(256) void u_kernel(const float* __restrict__ p,
                                                const float* __restrict__ V,
                                                float* __restrict__ u) {
  const int bt = blockIdx.x;                 // 4
  const int ct = blockIdx.y;                 // 16
  const int tid = threadIdx.x;
  const int c = ct * 64 + (tid & 63);
  const int cr = (c < CC) ? c : (CC - 1);
  const int bq = tid >> 6;
  __shared__ __attribute__((aligned(16))) float ps[16 * CC];    // 62.5KB
  for (int i = tid * 4; i < 16 * CC; i += 1024)
    *(float4*)&ps[i] = *(const float4*)&p[(size_t)(bt * 16) * CC + i];
  __syncthreads();
  const float4* Vr = (const float4*)(V + (size_t)cr * 1024);
  float acc[4] = {};
  #pragma unroll 8
  for (int j4 = 0; j4 < 250; ++j4) {
    float4 v = Vr[j4];
    #pragma unroll
    for (int i = 0; i < 4; ++i) {
      const float4 pp = *(const float4*)&ps[(bq * 4 + i) * CC + j4 * 4];
      acc[i] += pp.x*v.x + pp.y*v.y + pp.z*v.z + pp.w*v.w;
    }
  }
  if (c < CC) {
    #pragma unroll
    for (int i = 0; i < 4; ++i)
      u[(bt * 16 + bq * 4 + i) * CC + c] = acc[i];
  }
}

// ---------------------------------------------------------------- scan: per (b,j) argmax_c of logits[c] + s_j*(u[c] - V[j,c])
__global__ __launch_bounds__(256) void scan_kernel(const float* __restrict__ logits,
                                                   const float* __restrict__ u,
                                                   const float* __restrict__ p,
                                                   const float* __restrict__ AE,
                                                   const float* __restrict__ An2,
                                                   const float* __restrict__ En2,
                                                   const float* __restrict__ V,
                                                   int* __restrict__ pm) {
  const int b = blockIdx.x, jb = blockIdx.y;   // jb < 32
  const int tid = threadIdx.x, w = tid >> 6, lane = tid & 63;
  __shared__ __attribute__((aligned(16))) float4 Ls4[256], Us4[256];
  __shared__ float se[4];
  __shared__ float sGn2;
  const float4* Lg = (const float4*)(logits + b * CC);
  const float4* Ug = (const float4*)(u + b * CC);
  float part = 0.f;
  if (tid < 250) {
    float4 l4 = Lg[tid], u4 = Ug[tid];
    float4 p4 = ((const float4*)(p + b * CC))[tid];
    Ls4[tid] = l4; Us4[tid] = u4;
    part = p4.x*u4.x + p4.y*u4.y + p4.z*u4.z + p4.w*u4.w;
  } else {
    Ls4[tid] = float4{0.f,0.f,0.f,0.f};
    Us4[tid] = float4{0.f,0.f,0.f,0.f};
  }
  #pragma unroll
  for (int o = 1; o < 64; o <<= 1) part += __shfl_xor(part, o);
  if (lane == 0) se[w] = part;
  __syncthreads();
  if (tid == 0) sGn2 = se[0] + se[1] + se[2] + se[3];
  __syncthreads();

  const float en2 = En2[b], gn2b = sGn2;
  const float* Usf = (const float*)Us4;
  for (int jj = 0; jj < 8; ++jj) {
    int j = jb * 32 + w * 8 + jj;
    if (j >= CC) break;                         // uniform per wave
    float zn2 = An2[j] - 2.0f * AE[b * CC + j] + en2;
    float gn2 = gn2b - 2.0f * Usf[j] + V[(size_t)j * 1024 + j];
    float sj = (EPSA * sqrtf(zn2)) / sqrtf(gn2);
    float best = -3.402823466e38f; int bi = 0;
    const float4* Vr = (const float4*)(V + (size_t)j * 1024);
    #pragma unroll
    for (int it = 0; it < 4; ++it) {
      int idx = it * 64 + lane;
      int c0 = idx * 4;
      float4 vv = Vr[idx];
      float4 l4 = Ls4[idx];
      float4 u4 = Us4[idx];
      float vals[4] = { l4.x + sj * (u4.x - vv.x),
                        l4.y + sj * (u4.y - vv.y),
                        l4.z + sj * (u4.z - vv.z),
                        l4.w + sj * (u4.w - vv.w) };
      #pragma unroll
      for (int comp = 0; comp < 4; ++comp) {
        int c = c0 + comp;
        if (c < CC && vals[comp] > best) { best = vals[comp]; bi = c; }
      }
    }
    #pragma unroll
    for (int o = 1; o < 64; o <<= 1) {
      float ov = __shfl_xor(best, o);
      int   oi = __shfl_xor(bi, o);
      if (ov > best || (ov == best && oi < bi)) { best = ov; bi = oi; }
    }
    if (lane == 0) pm[b * CC + j] = bi;
  }
}

// ---------------------------------------------------------------- counts + all(counts < 3)
__global__ __launch_bounds__(256) void counts_kernel(const int* __restrict__ pm,
                                                     const int* __restrict__ pred,
                                                     float* __restrict__ out) {
  int b = blockIdx.x, t = threadIdx.x;
  __shared__ int cnt[CC];
  __shared__ int bad;
  for (int c = t; c < CC; c += 256) cnt[c] = 0;
  if (t == 0) bad = 0;
  __syncthreads();
  if (t == 0) atomicAdd(&cnt[pred[b]], 1);
  for (int j = t; j < CC; j += 256) atomicAdd(&cnt[pm[b * CC + j]], 1);
  __syncthreads();
  for (int c = t; c < CC; c += 256) if (cnt[c] >= NSIM) bad = 1;
  __syncthreads();
  if (t == 0) out[b] = bad ? 0.0f : 1.0f;
}

// ---------------------------------------------------------------- launch
extern "C" void kernel_launch(void* const* d_in, const int* in_sizes, int n_in,
                              void* d_out, int out_size, void* d_ws, size_t ws_size,
                              hipStream_t stream) {
  const float* x       = (const float*)d_in[0];
  const float* W_emb   = (const float*)d_in[1];
  const float* b_emb   = (const float*)d_in[2];
  const float* W_fc    = (const float*)d_in[3];
  const float* b_fc    = (const float*)d_in[4];
  const float* anchors = (const float*)d_in[5];
  float* out = (float*)d_out;

  // workspace carve (~7.0 MB), all 16B-aligned
  float* emb    = (float*)d_ws;               // 64*768
  float* logits = emb + BB * DD;              // 64*1000
  float* p      = logits + BB * CC;           // 64*1000
  float* u      = p + BB * CC;                // 64*1000
  float* AE     = u + BB * CC;                // 64*1000
  float* An2    = AE + BB * CC;               // 1024
  float* En2    = An2 + 1024;                 // 64
  int*   pred   = (int*)(En2 + 64);           // 64
  int*   pm     = pred + 64;                  // 64*1000
  short* Bp     = (short*)(pm + BB * CC);     // 98304*8 bf16 bits (1.57 MB)
  float* V      = (float*)(Bp + 64 * 24 * 64 * 8);  // 1024*1024 f32 (4 MB)

  hipLaunchKernelGGL(packAn2_kernel, dim3(634), dim3(256), 0, stream, W_fc, anchors, Bp, An2);
  hipLaunchKernelGGL(emb_kernel,     dim3(4, 12), dim3(256), 0, stream, x, W_emb, b_emb, emb);
  hipLaunchKernelGGL(V_kernel,       dim3(16, 16), dim3(256), 0, stream, Bp, V);
  hipLaunchKernelGGL(logitsAE_kernel,dim3(4, 16), dim3(256), 0, stream,
                     emb, W_fc, anchors, b_fc, logits, AE);
  hipLaunchKernelGGL(softmax_kernel, dim3(BB),    dim3(256), 0, stream, logits, emb, p, pred, En2);
  hipLaunchKernelGGL(u_kernel,       dim3(4, 16), dim3(256), 0, stream, p, V, u);
  hipLaunchKernelGGL(scan_kernel,    dim3(BB, 32), dim3(256), 0, stream,
                     logits, u, p, AE, An2, En2, V, pm);
  hipLaunchKernelGGL(counts_kernel,  dim3(BB), dim3(256), 0, stream, pm, pred, out);
}

// Round 11
// 179.995 us; speedup vs baseline: 1.2065x; 1.1200x over previous
//
#include <hip/hip_runtime.h>
#include <stdint.h>
#include <stddef.h>

#define BB 64
#define DIN 1024
#define DD 768
#define CC 1000
#define EPSA 0.1f
#define NSIM 3

typedef short  s16x8 __attribute__((ext_vector_type(8)));
typedef float  f32x4 __attribute__((ext_vector_type(4)));

static __device__ __forceinline__ unsigned short f2bf_rne(float x) {
  unsigned u = __float_as_uint(x);
  return (unsigned short)((u + 0x7FFFu + ((u >> 16) & 1u)) >> 16);
}

// ---------------------------------------------------------------- fused prep: pack W_fc (bf16 frag) | An2 | emb
// blocks 0..383: Bp; 384..633: An2; 634..825: emb (b-tile 4 x d-tile 64)
__global__ __launch_bounds__(256) void prep_kernel(const float* __restrict__ W_fc,
                                                   const float* __restrict__ anchors,
                                                   const float* __restrict__ x,
                                                   const float* __restrict__ W_emb,
                                                   const float* __restrict__ b_emb,
                                                   short* __restrict__ Bp,
                                                   float* __restrict__ An2,
                                                   float* __restrict__ emb) {
  const int blk = blockIdx.x;
  const int tid = threadIdx.x;
  __shared__ __attribute__((aligned(16))) float xs[4 * DIN];    // 16KB (emb branch)
  if (blk < 384) {
    int gid = blk * 256 + tid;             // 64*24*64 = 98304
    int lane = gid & 63;
    int ks   = (gid >> 6) % 24;
    int nt   = gid / (64 * 24);
    int c  = nt * 16 + (lane & 15);
    int k0 = ks * 32 + (lane >> 4) * 8;
    s16x8 vh;
    #pragma unroll
    for (int r = 0; r < 8; ++r) {
      float w = (c < CC) ? W_fc[(size_t)c * DD + k0 + r] : 0.0f;
      vh[r] = (short)f2bf_rne(w);
    }
    ((s16x8*)Bp)[gid] = vh;
  } else if (blk < 634) {
    int w = tid >> 6, lane = tid & 63;
    int j = (blk - 384) * 4 + w;           // < 1000
    const float4* ar = (const float4*)(anchors + (size_t)j * DD);
    float an = 0.f;
    for (int k4 = lane; k4 < DD / 4; k4 += 64) {
      float4 a = ar[k4];
      an += a.x*a.x + a.y*a.y + a.z*a.z + a.w*a.w;
    }
    #pragma unroll
    for (int o = 1; o < 64; o <<= 1) an += __shfl_xor(an, o);
    if (lane == 0) An2[j] = an;
  } else {
    int e = blk - 634;                     // 0..191
    int bt = e / 12, dt = e % 12;
    int d = dt * 64 + (tid & 63);
    int i = tid >> 6;                      // b = bt*4 + i
    for (int idx = tid * 4; idx < 4 * DIN; idx += 1024)
      *(float4*)&xs[idx] = *(const float4*)&x[(size_t)(bt * 4) * DIN + idx];
    __syncthreads();
    const float4* wr = (const float4*)(W_emb + (size_t)d * DIN);
    const float4* xr = (const float4*)&xs[i * DIN];
    float acc = 0.f;
    #pragma unroll 8
    for (int k4 = 0; k4 < DIN / 4; ++k4) {
      float4 w = wr[k4];
      float4 xv = xr[k4];
      acc += xv.x*w.x + xv.y*w.y + xv.z*w.z + xv.w*w.w;
    }
    emb[(size_t)(bt * 4 + i) * DD + d] = acc + b_emb[d];
  }
}

// ---------------------------------------------------------------- V = W_fc @ W_fc^T  [1024,1024] (bf16 MFMA, fp32 out)
__global__ __launch_bounds__(256) void V_kernel(const short* __restrict__ Bp,
                                                float* __restrict__ V) {
  const int tid = threadIdx.x;
  const int w = tid >> 6, lane = tid & 63;
  const int rnt = blockIdx.x * 4 + w;       // rows rnt*16..+15
  const int cb  = blockIdx.y;               // cols cb*64..+63
  const s16x8* BH = (const s16x8*)Bp;
  f32x4 acc[4] = {};
  for (int ks = 0; ks < 24; ++ks) {
    s16x8 a = BH[(rnt * 24 + ks) * 64 + lane];
    #pragma unroll
    for (int nf = 0; nf < 4; ++nf) {
      s16x8 bf = BH[((cb * 4 + nf) * 24 + ks) * 64 + lane];
      acc[nf] = __builtin_amdgcn_mfma_f32_16x16x32_bf16(a, bf, acc[nf], 0, 0, 0);
    }
  }
  const int r0 = rnt * 16 + (lane >> 4) * 4;   // C/D: row=(lane>>4)*4+reg, col=lane&15 [m89]
  const int c0 = cb * 64 + (lane & 15);
  #pragma unroll
  for (int nf = 0; nf < 4; ++nf)
    #pragma unroll
    for (int rr = 0; rr < 4; ++rr)
      V[(size_t)(r0 + rr) * 1024 + c0 + nf * 16] = acc[nf][rr];
}

// ---------------------------------------------------------------- logits + AE  (b-tile 4; thread: one (b,c), 2 streams)
__global__ __launch_bounds__(256) void logitsAE_kernel(const float* __restrict__ emb,
                                                       const float* __restrict__ W_fc,
                                                       const float* __restrict__ anchors,
                                                       const float* __restrict__ b_fc,
                                                       float* __restrict__ logits,
                                                       float* __restrict__ AE) {
  const int bt = blockIdx.x;                 // 16
  const int ct = blockIdx.y;                 // 16
  const int tid = threadIdx.x;
  const int c = ct * 64 + (tid & 63);
  const int cr = (c < CC) ? c : (CC - 1);
  const int i = tid >> 6;                    // b = bt*4 + i
  __shared__ __attribute__((aligned(16))) float es[4 * DD];     // 12KB
  for (int idx = tid * 4; idx < 4 * DD; idx += 1024)
    *(float4*)&es[idx] = *(const float4*)&emb[(size_t)(bt * 4) * DD + idx];
  __syncthreads();
  const float4* wr = (const float4*)(W_fc + (size_t)cr * DD);
  const float4* ar = (const float4*)(anchors + (size_t)cr * DD);
  const float4* er = (const float4*)&es[i * DD];
  float accL = 0.f, accA = 0.f;
  #pragma unroll 8
  for (int k4 = 0; k4 < DD / 4; ++k4) {
    float4 w = wr[k4];
    float4 a = ar[k4];
    float4 e = er[k4];
    accL += e.x*w.x + e.y*w.y + e.z*w.z + e.w*w.w;
    accA += e.x*a.x + e.y*a.y + e.z*a.z + e.w*a.w;
  }
  if (c < CC) {
    int b = bt * 4 + i;
    logits[b * CC + c] = accL + b_fc[c];
    AE[b * CC + c]     = accA;
  }
}

// ---------------------------------------------------------------- softmax + argmax(logits) + En2
__global__ __launch_bounds__(256) void softmax_kernel(const float* __restrict__ logits,
                                                      const float* __restrict__ emb,
                                                      float* __restrict__ p,
                                                      int* __restrict__ pred,
                                                      float* __restrict__ En2) {
  int b = blockIdx.x, t = threadIdx.x;
  __shared__ float smax[256];
  __shared__ int   sidx[256];
  __shared__ float ssum[256];
  {
    float pe = 0.f;
    for (int k = t; k < DD; k += 256) { float e = emb[b * DD + k]; pe += e * e; }
    #pragma unroll
    for (int o = 1; o < 64; o <<= 1) pe += __shfl_xor(pe, o);
    __shared__ float se[4];
    if ((t & 63) == 0) se[t >> 6] = pe;
    __syncthreads();
    if (t == 0) En2[b] = se[0] + se[1] + se[2] + se[3];
  }
  float m = -3.402823466e38f; int mi = 0;
  for (int c = t; c < CC; c += 256) {
    float v = logits[b * CC + c];
    if (v > m) { m = v; mi = c; }
  }
  smax[t] = m; sidx[t] = mi;
  __syncthreads();
  for (int o = 128; o > 0; o >>= 1) {
    if (t < o) {
      float v2 = smax[t + o]; int i2 = sidx[t + o];
      if (v2 > smax[t] || (v2 == smax[t] && i2 < sidx[t])) { smax[t] = v2; sidx[t] = i2; }
    }
    __syncthreads();
  }
  float M = smax[0];
  if (t == 0) pred[b] = sidx[0];
  float sum = 0.f;
  for (int c = t; c < CC; c += 256) sum += expf(logits[b * CC + c] - M);
  ssum[t] = sum;
  __syncthreads();
  for (int o = 128; o > 0; o >>= 1) {
    if (t < o) ssum[t] += ssum[t + o];
    __syncthreads();
  }
  float S = ssum[0];
  for (int c = t; c < CC; c += 256) p[b * CC + c] = expf(logits[b * CC + c] - M) / S;
}

// ---------------------------------------------------------------- u[b,c] = sum_j p[b,j] * V[c,j]  (b-tile 4)
__global__ __launch_bounds__(256) void u_kernel(const float* __restrict__ p,
                                                const float* __restrict__ V,
                                                float* __restrict__ u) {
  const int bt = blockIdx.x;                 // 16
  const int ct = blockIdx.y;                 // 16
  const int tid = threadIdx.x;
  const int c = ct * 64 + (tid & 63);
  const int cr = (c < CC) ? c : (CC - 1);
  const int i = tid >> 6;                    // b = bt*4 + i
  __shared__ __attribute__((aligned(16))) float ps[4 * CC];     // 16KB
  for (int idx = tid * 4; idx < 4 * CC; idx += 1024)
    *(float4*)&ps[idx] = *(const float4*)&p[(size_t)(bt * 4) * CC + idx];
  __syncthreads();
  const float4* Vr = (const float4*)(V + (size_t)cr * 1024);
  const float4* pr = (const float4*)&ps[i * CC];
  float acc = 0.f;
  #pragma unroll 8
  for (int j4 = 0; j4 < 250; ++j4) {
    float4 v = Vr[j4];
    float4 pp = pr[j4];
    acc += pp.x*v.x + pp.y*v.y + pp.z*v.z + pp.w*v.w;
  }
  if (c < CC) u[(bt * 4 + i) * CC + c] = acc;
}

// ---------------------------------------------------------------- scan: per (b,j) argmax_c of logits[c] + s_j*(u[c] - V[j,c])
__global__ __launch_bounds__(256) void scan_kernel(const float* __restrict__ logits,
                                                   const float* __restrict__ u,
                                                   const float* __restrict__ p,
                                                   const float* __restrict__ AE,
                                                   const float* __restrict__ An2,
                                                   const float* __restrict__ En2,
                                                   const float* __restrict__ V,
                                                   int* __restrict__ pm) {
  const int b = blockIdx.x, jb = blockIdx.y;   // jb < 32
  const int tid = threadIdx.x, w = tid >> 6, lane = tid & 63;
  __shared__ __attribute__((aligned(16))) float4 Ls4[256], Us4[256];
  __shared__ float se[4];
  __shared__ float sGn2;
  const float4* Lg = (const float4*)(logits + b * CC);
  const float4* Ug = (const float4*)(u + b * CC);
  float part = 0.f;
  if (tid < 250) {
    float4 l4 = Lg[tid], u4 = Ug[tid];
    float4 p4 = ((const float4*)(p + b * CC))[tid];
    Ls4[tid] = l4; Us4[tid] = u4;
    part = p4.x*u4.x + p4.y*u4.y + p4.z*u4.z + p4.w*u4.w;
  } else {
    Ls4[tid] = float4{0.f,0.f,0.f,0.f};
    Us4[tid] = float4{0.f,0.f,0.f,0.f};
  }
  #pragma unroll
  for (int o = 1; o < 64; o <<= 1) part += __shfl_xor(part, o);
  if (lane == 0) se[w] = part;
  __syncthreads();
  if (tid == 0) sGn2 = se[0] + se[1] + se[2] + se[3];
  __syncthreads();

  const float en2 = En2[b], gn2b = sGn2;
  const float* Usf = (const float*)Us4;
  for (int jj = 0; jj < 8; ++jj) {
    int j = jb * 32 + w * 8 + jj;
    if (j >= CC) break;                         // uniform per wave
    float zn2 = An2[j] - 2.0f * AE[b * CC + j] + en2;
    float gn2 = gn2b - 2.0f * Usf[j] + V[(size_t)j * 1024 + j];
    float sj = (EPSA * sqrtf(zn2)) / sqrtf(gn2);
    float best = -3.402823466e38f; int bi = 0;
    const float4* Vr = (const float4*)(V + (size_t)j * 1024);
    #pragma unroll
    for (int it = 0; it < 4; ++it) {
      int idx = it * 64 + lane;
      int c0 = idx * 4;
      float4 vv = Vr[idx];
      float4 l4 = Ls4[idx];
      float4 u4 = Us4[idx];
      float vals[4] = { l4.x + sj * (u4.x - vv.x),
                        l4.y + sj * (u4.y - vv.y),
                        l4.z + sj * (u4.z - vv.z),
                        l4.w + sj * (u4.w - vv.w) };
      #pragma unroll
      for (int comp = 0; comp < 4; ++comp) {
        int c = c0 + comp;
        if (c < CC && vals[comp] > best) { best = vals[comp]; bi = c; }
      }
    }
    #pragma unroll
    for (int o = 1; o < 64; o <<= 1) {
      float ov = __shfl_xor(best, o);
      int   oi = __shfl_xor(bi, o);
      if (ov > best || (ov == best && oi < bi)) { best = ov; bi = oi; }
    }
    if (lane == 0) pm[b * CC + j] = bi;
  }
}

// ---------------------------------------------------------------- counts + all(counts < 3)
__global__ __launch_bounds__(256) void counts_kernel(const int* __restrict__ pm,
                                                     const int* __restrict__ pred,
                                                     float* __restrict__ out) {
  int b = blockIdx.x, t = threadIdx.x;
  __shared__ int cnt[CC];
  __shared__ int bad;
  for (int c = t; c < CC; c += 256) cnt[c] = 0;
  if (t == 0) bad = 0;
  __syncthreads();
  if (t == 0) atomicAdd(&cnt[pred[b]], 1);
  for (int j = t; j < CC; j += 256) atomicAdd(&cnt[pm[b * CC + j]], 1);
  __syncthreads();
  for (int c = t; c < CC; c += 256) if (cnt[c] >= NSIM) bad = 1;
  __syncthreads();
  if (t == 0) out[b] = bad ? 0.0f : 1.0f;
}

// ---------------------------------------------------------------- launch
extern "C" void kernel_launch(void* const* d_in, const int* in_sizes, int n_in,
                              void* d_out, int out_size, void* d_ws, size_t ws_size,
                              hipStream_t stream) {
  const float* x       = (const float*)d_in[0];
  const float* W_emb   = (const float*)d_in[1];
  const float* b_emb   = (const float*)d_in[2];
  const float* W_fc    = (const float*)d_in[3];
  const float* b_fc    = (const float*)d_in[4];
  const float* anchors = (const float*)d_in[5];
  float* out = (float*)d_out;

  // workspace carve (~7.0 MB), all 16B-aligned
  float* emb    = (float*)d_ws;               // 64*768
  float* logits = emb + BB * DD;              // 64*1000
  float* p      = logits + BB * CC;           // 64*1000
  float* u      = p + BB * CC;                // 64*1000
  float* AE     = u + BB * CC;                // 64*1000
  float* An2    = AE + BB * CC;               // 1024
  float* En2    = An2 + 1024;                 // 64
  int*   pred   = (int*)(En2 + 64);           // 64
  int*   pm     = pred + 64;                  // 64*1000
  short* Bp     = (short*)(pm + BB * CC);     // 98304*8 bf16 bits (1.57 MB)
  float* V      = (float*)(Bp + 64 * 24 * 64 * 8);  // 1024*1024 f32 (4 MB)

  hipLaunchKernelGGL(prep_kernel,    dim3(826), dim3(256), 0, stream,
                     W_fc, anchors, x, W_emb, b_emb, Bp, An2, emb);
  hipLaunchKernelGGL(V_kernel,       dim3(16, 16), dim3(256), 0, stream, Bp, V);
  hipLaunchKernelGGL(logitsAE_kernel,dim3(16, 16), dim3(256), 0, stream,
                     emb, W_fc, anchors, b_fc, logits, AE);
  hipLaunchKernelGGL(softmax_kernel, dim3(BB),    dim3(256), 0, stream, logits, emb, p, pred, En2);
  hipLaunchKernelGGL(u_kernel,       dim3(16, 16), dim3(256), 0, stream, p, V, u);
  hipLaunchKernelGGL(scan_kernel,    dim3(BB, 32), dim3(256), 0, stream,
                     logits, u, p, AE, An2, En2, V, pm);
  hipLaunchKernelGGL(counts_kernel,  dim3(BB), dim3(256), 0, stream, pm, pred, out);
}

// Round 12
// 118.289 us; speedup vs baseline: 1.8359x; 1.5217x over previous
//
#include <hip/hip_runtime.h>
#include <stdint.h>
#include <stddef.h>

#define BB 64
#define DIN 1024
#define DD 768
#define CC 1000
#define EPSA 0.1f
#define NSIM 3

typedef short  s16x8 __attribute__((ext_vector_type(8)));
typedef float  f32x4 __attribute__((ext_vector_type(4)));

static __device__ __forceinline__ unsigned short f2bf_rne(float x) {
  unsigned u = __float_as_uint(x);
  return (unsigned short)((u + 0x7FFFu + ((u >> 16) & 1u)) >> 16);
}
static __device__ __forceinline__ float bf2f(unsigned short h) {
  return __uint_as_float(((unsigned)h) << 16);
}

// ---------------------------------------------------------------- prep: pack {W_fc,anchors,W_emb,x} to bf16 frags + An2
// frag[nt][ks][lane][reg]: row = nt*16+(lane&15), k = ks*32+(lane>>4)*8+reg
__global__ __launch_bounds__(256) void prep_kernel(const float* __restrict__ W_fc,
                                                   const float* __restrict__ anchors,
                                                   const float* __restrict__ W_emb,
                                                   const float* __restrict__ x,
                                                   short* __restrict__ Bp, short* __restrict__ Ap,
                                                   short* __restrict__ Ip, short* __restrict__ Xp,
                                                   float* __restrict__ An2) {
  const int blk = blockIdx.x, tid = threadIdx.x;
  if (blk < 1184) {
    const float* src; short* dst; int KS, nrow, gid;
    if (blk < 384)       { src = W_fc;    dst = Bp; KS = 24; nrow = CC;  gid = blk * 256 + tid; }
    else if (blk < 768)  { src = anchors; dst = Ap; KS = 24; nrow = CC;  gid = (blk - 384) * 256 + tid; }
    else if (blk < 1152) { src = W_emb;   dst = Ip; KS = 32; nrow = DD;  gid = (blk - 768) * 256 + tid; }
    else                 { src = x;       dst = Xp; KS = 32; nrow = BB;  gid = (blk - 1152) * 256 + tid; }
    int lane = gid & 63;
    int ks   = (gid >> 6) % KS;
    int nt   = gid / (64 * KS);
    int row  = nt * 16 + (lane & 15);
    int k0   = ks * 32 + (lane >> 4) * 8;
    int stride = KS * 32;
    s16x8 v;
    #pragma unroll
    for (int r = 0; r < 8; ++r) {
      float w = (row < nrow) ? src[(size_t)row * stride + k0 + r] : 0.0f;
      v[r] = (short)f2bf_rne(w);
    }
    ((s16x8*)dst)[gid] = v;
  } else {
    int w = tid >> 6, lane = tid & 63;
    int j = (blk - 1184) * 4 + w;          // < 1000
    const float4* ar = (const float4*)(anchors + (size_t)j * DD);
    float an = 0.f;
    for (int k4 = lane; k4 < DD / 4; k4 += 64) {
      float4 a = ar[k4];
      an += a.x*a.x + a.y*a.y + a.z*a.z + a.w*a.w;
    }
    #pragma unroll
    for (int o = 1; o < 64; o <<= 1) an += __shfl_xor(an, o);
    if (lane == 0) An2[j] = an;
  }
}

// ---------------------------------------------------------------- embV: blocks 0..255 -> Vb = bf16(W@W^T); 256..267 -> emb MFMA
__global__ __launch_bounds__(256) void embV_kernel(const short* __restrict__ Bp,
                                                   const short* __restrict__ Ip,
                                                   const short* __restrict__ Xp,
                                                   const float* __restrict__ b_emb,
                                                   unsigned short* __restrict__ Vb,
                                                   float* __restrict__ emb) {
  const int tid = threadIdx.x, w = tid >> 6, lane = tid & 63;
  if (blockIdx.x < 256) {
    const int bx = blockIdx.x & 15, cb = blockIdx.x >> 4;
    const int rnt = bx * 4 + w;
    const s16x8* BH = (const s16x8*)Bp;
    f32x4 acc[4] = {};
    for (int ks = 0; ks < 24; ++ks) {
      s16x8 a = BH[(rnt * 24 + ks) * 64 + lane];
      #pragma unroll
      for (int nf = 0; nf < 4; ++nf)
        acc[nf] = __builtin_amdgcn_mfma_f32_16x16x32_bf16(a, BH[((cb * 4 + nf) * 24 + ks) * 64 + lane], acc[nf], 0, 0, 0);
    }
    const int r0 = rnt * 16 + (lane >> 4) * 4;   // C/D: row=(lane>>4)*4+reg, col=lane&15 [m89]
    const int c0 = cb * 64 + (lane & 15);
    #pragma unroll
    for (int nf = 0; nf < 4; ++nf)
      #pragma unroll
      for (int rr = 0; rr < 4; ++rr)
        Vb[(size_t)(r0 + rr) * 1024 + c0 + nf * 16] = f2bf_rne(acc[nf][rr]);
  } else {
    const int g = blockIdx.x - 256;             // 0..11
    const int nfr = g * 4 + w;                  // 0..47
    const s16x8* XH = (const s16x8*)Xp;
    const s16x8* IH = (const s16x8*)Ip;
    f32x4 acc[4] = {};
    for (int ks = 0; ks < 32; ++ks) {
      s16x8 b = IH[(nfr * 32 + ks) * 64 + lane];
      #pragma unroll
      for (int mt = 0; mt < 4; ++mt)
        acc[mt] = __builtin_amdgcn_mfma_f32_16x16x32_bf16(XH[(mt * 32 + ks) * 64 + lane], b, acc[mt], 0, 0, 0);
    }
    const int d = nfr * 16 + (lane & 15);       // < 768
    const float be = b_emb[d];
    #pragma unroll
    for (int mt = 0; mt < 4; ++mt)
      #pragma unroll
      for (int rr = 0; rr < 4; ++rr)
        emb[(size_t)(mt * 16 + (lane >> 4) * 4 + rr) * DD + d] = acc[mt][rr] + be;
  }
}

// ---------------------------------------------------------------- packmid: blocks 0..511 Vp (from Vb); 512..535 Ep (from emb)
__global__ __launch_bounds__(256) void packmid_kernel(const unsigned short* __restrict__ Vb,
                                                      const float* __restrict__ emb,
                                                      short* __restrict__ Vp,
                                                      short* __restrict__ Ep) {
  const int blk = blockIdx.x, tid = threadIdx.x;
  if (blk < 512) {
    int gid = blk * 256 + tid;                 // 64 nt x 32 ks x 64 = 131072
    int lane = gid & 63, ks = (gid >> 6) % 32, nt = gid / (64 * 32);
    int row = nt * 16 + (lane & 15);
    int k0  = ks * 32 + (lane >> 4) * 8;
    ((s16x8*)Vp)[gid] = *(const s16x8*)(Vb + (size_t)row * 1024 + k0);   // lossless repack
  } else {
    int gid = (blk - 512) * 256 + tid;         // 4 mt x 24 ks x 64 = 6144
    if (gid >= 4 * 24 * 64) return;
    int lane = gid & 63, ks = (gid >> 6) % 24, mt = gid / (64 * 24);
    int row = mt * 16 + (lane & 15);
    int k0  = ks * 32 + (lane >> 4) * 8;
    s16x8 v;
    #pragma unroll
    for (int r = 0; r < 8; ++r) v[r] = (short)f2bf_rne(emb[(size_t)row * DD + k0 + r]);
    ((s16x8*)Ep)[gid] = v;
  }
}

// ---------------------------------------------------------------- logits + AE via MFMA (64 blocks x 1 wave)
__global__ __launch_bounds__(64) void logitsAE_kernel(const short* __restrict__ Ep,
                                                      const short* __restrict__ Bp,
                                                      const short* __restrict__ Ap,
                                                      const float* __restrict__ b_fc,
                                                      float* __restrict__ logits,
                                                      float* __restrict__ AE) {
  const int nfr = blockIdx.x;                  // 0..63
  const int lane = threadIdx.x;
  const s16x8* E = (const s16x8*)Ep;
  const s16x8* B = (const s16x8*)Bp;
  const s16x8* A = (const s16x8*)Ap;
  f32x4 accL[4] = {}, accA[4] = {};
  for (int ks = 0; ks < 24; ++ks) {
    s16x8 bW = B[(nfr * 24 + ks) * 64 + lane];
    s16x8 bA = A[(nfr * 24 + ks) * 64 + lane];
    #pragma unroll
    for (int mt = 0; mt < 4; ++mt) {
      s16x8 a = E[(mt * 24 + ks) * 64 + lane];
      accL[mt] = __builtin_amdgcn_mfma_f32_16x16x32_bf16(a, bW, accL[mt], 0, 0, 0);
      accA[mt] = __builtin_amdgcn_mfma_f32_16x16x32_bf16(a, bA, accA[mt], 0, 0, 0);
    }
  }
  const int c = nfr * 16 + (lane & 15);
  if (c < CC) {
    const float bf = b_fc[c];
    #pragma unroll
    for (int mt = 0; mt < 4; ++mt)
      #pragma unroll
      for (int rr = 0; rr < 4; ++rr) {
        int b = mt * 16 + (lane >> 4) * 4 + rr;
        logits[b * CC + c] = accL[mt][rr] + bf;
        AE[b * CC + c]     = accA[mt][rr];
      }
  }
}

// ---------------------------------------------------------------- softmax + argmax + En2 + Pp (bf16 frag of p)
__global__ __launch_bounds__(256) void softmax_kernel(const float* __restrict__ logits,
                                                      const float* __restrict__ emb,
                                                      float* __restrict__ p,
                                                      short* __restrict__ Pp,
                                                      int* __restrict__ pred,
                                                      float* __restrict__ En2) {
  int b = blockIdx.x, t = threadIdx.x;
  __shared__ float smax[256];
  __shared__ int   sidx[256];
  __shared__ float ssum[256];
  {
    float pe = 0.f;
    for (int k = t; k < DD; k += 256) { float e = emb[b * DD + k]; pe += e * e; }
    #pragma unroll
    for (int o = 1; o < 64; o <<= 1) pe += __shfl_xor(pe, o);
    __shared__ float se[4];
    if ((t & 63) == 0) se[t >> 6] = pe;
    __syncthreads();
    if (t == 0) En2[b] = se[0] + se[1] + se[2] + se[3];
  }
  float m = -3.402823466e38f; int mi = 0;
  for (int c = t; c < CC; c += 256) {
    float v = logits[b * CC + c];
    if (v > m) { m = v; mi = c; }
  }
  smax[t] = m; sidx[t] = mi;
  __syncthreads();
  for (int o = 128; o > 0; o >>= 1) {
    if (t < o) {
      float v2 = smax[t + o]; int i2 = sidx[t + o];
      if (v2 > smax[t] || (v2 == smax[t] && i2 < sidx[t])) { smax[t] = v2; sidx[t] = i2; }
    }
    __syncthreads();
  }
  float M = smax[0];
  if (t == 0) pred[b] = sidx[0];
  float sum = 0.f;
  for (int c = t; c < CC; c += 256) sum += expf(logits[b * CC + c] - M);
  ssum[t] = sum;
  __syncthreads();
  for (int o = 128; o > 0; o >>= 1) {
    if (t < o) ssum[t] += ssum[t + o];
    __syncthreads();
  }
  float S = ssum[0];
  const int mt = b >> 4, blo = b & 15;
  for (int j = t; j < CC; j += 256) {
    float pj = expf(logits[b * CC + j] - M) / S;
    p[b * CC + j] = pj;
    // Pp frag slot: lane = ((j>>3)&3)*16 + blo, ks = j>>5, reg = j&7
    size_t fi = ((size_t)(mt * 32 + (j >> 5)) * 64 + ((j >> 3) & 3) * 16 + blo) * 8 + (j & 7);
    Pp[fi] = (short)f2bf_rne(pj);
  }
  if (t < 24) {     // zero k-pad 1000..1023
    int j = 1000 + t;
    size_t fi = ((size_t)(mt * 32 + (j >> 5)) * 64 + ((j >> 3) & 3) * 16 + blo) * 8 + (j & 7);
    Pp[fi] = 0;
  }
}

// ---------------------------------------------------------------- u = p @ V via MFMA (V symmetric; 64 blocks x 1 wave)
__global__ __launch_bounds__(64) void u_kernel(const short* __restrict__ Pp,
                                               const short* __restrict__ Vp,
                                               float* __restrict__ u) {
  const int nfr = blockIdx.x;                  // 0..63
  const int lane = threadIdx.x;
  const s16x8* P = (const s16x8*)Pp;
  const s16x8* V = (const s16x8*)Vp;
  f32x4 acc[4] = {};
  for (int ks = 0; ks < 32; ++ks) {
    s16x8 b = V[(nfr * 32 + ks) * 64 + lane];
    #pragma unroll
    for (int mt = 0; mt < 4; ++mt)
      acc[mt] = __builtin_amdgcn_mfma_f32_16x16x32_bf16(P[(mt * 32 + ks) * 64 + lane], b, acc[mt], 0, 0, 0);
  }
  const int c = nfr * 16 + (lane & 15);
  if (c < CC) {
    #pragma unroll
    for (int mt = 0; mt < 4; ++mt)
      #pragma unroll
      for (int rr = 0; rr < 4; ++rr)
        u[(mt * 16 + (lane >> 4) * 4 + rr) * CC + c] = acc[mt][rr];
  }
}

// ---------------------------------------------------------------- scan: per (b,j) argmax_c of logits[c] + s_j*(u[c] - V[j,c])
__global__ __launch_bounds__(256) void scan_kernel(const float* __restrict__ logits,
                                                   const float* __restrict__ u,
                                                   const float* __restrict__ p,
                                                   const float* __restrict__ AE,
                                                   const float* __restrict__ An2,
                                                   const float* __restrict__ En2,
                                                   const unsigned short* __restrict__ Vb,
                                                   int* __restrict__ pm) {
  const int b = blockIdx.x, jb = blockIdx.y;   // jb < 32
  const int tid = threadIdx.x, w = tid >> 6, lane = tid & 63;
  __shared__ __attribute__((aligned(16))) float4 Ls4[256], Us4[256];
  __shared__ float se[4];
  __shared__ float sGn2;
  const float4* Lg = (const float4*)(logits + b * CC);
  const float4* Ug = (const float4*)(u + b * CC);
  float part = 0.f;
  if (tid < 250) {
    float4 l4 = Lg[tid], u4 = Ug[tid];
    float4 p4 = ((const float4*)(p + b * CC))[tid];
    Ls4[tid] = l4; Us4[tid] = u4;
    part = p4.x*u4.x + p4.y*u4.y + p4.z*u4.z + p4.w*u4.w;
  } else {
    Ls4[tid] = float4{0.f,0.f,0.f,0.f};
    Us4[tid] = float4{0.f,0.f,0.f,0.f};
  }
  #pragma unroll
  for (int o = 1; o < 64; o <<= 1) part += __shfl_xor(part, o);
  if (lane == 0) se[w] = part;
  __syncthreads();
  if (tid == 0) sGn2 = se[0] + se[1] + se[2] + se[3];
  __syncthreads();

  const float en2 = En2[b], gn2b = sGn2;
  const float* Usf = (const float*)Us4;
  for (int jj = 0; jj < 8; ++jj) {
    int j = jb * 32 + w * 8 + jj;
    if (j >= CC) break;                         // uniform per wave
    float zn2 = An2[j] - 2.0f * AE[b * CC + j] + en2;
    float gn2 = gn2b - 2.0f * Usf[j] + bf2f(Vb[(size_t)j * 1024 + j]);
    float sj = (EPSA * sqrtf(zn2)) / sqrtf(gn2);
    float best = -3.402823466e38f; int bi = 0;
    const s16x8* Vr = (const s16x8*)(Vb + (size_t)j * 1024);
    #pragma unroll
    for (int it = 0; it < 2; ++it) {
      int idx = it * 64 + lane;                 // 0..127, c0 = idx*8
      int c0 = idx * 8;
      s16x8 v8 = Vr[idx];
      float4 la = Ls4[idx * 2], lb = Ls4[idx * 2 + 1];
      float4 ua = Us4[idx * 2], ub = Us4[idx * 2 + 1];
      float vals[8] = {
        la.x + sj * (ua.x - bf2f((unsigned short)v8[0])),
        la.y + sj * (ua.y - bf2f((unsigned short)v8[1])),
        la.z + sj * (ua.z - bf2f((unsigned short)v8[2])),
        la.w + sj * (ua.w - bf2f((unsigned short)v8[3])),
        lb.x + sj * (ub.x - bf2f((unsigned short)v8[4])),
        lb.y + sj * (ub.y - bf2f((unsigned short)v8[5])),
        lb.z + sj * (ub.z - bf2f((unsigned short)v8[6])),
        lb.w + sj * (ub.w - bf2f((unsigned short)v8[7]))
      };
      #pragma unroll
      for (int comp = 0; comp < 8; ++comp) {
        int c = c0 + comp;
        if (c < CC && vals[comp] > best) { best = vals[comp]; bi = c; }
      }
    }
    #pragma unroll
    for (int o = 1; o < 64; o <<= 1) {
      float ov = __shfl_xor(best, o);
      int   oi = __shfl_xor(bi, o);
      if (ov > best || (ov == best && oi < bi)) { best = ov; bi = oi; }
    }
    if (lane == 0) pm[b * CC + j] = bi;
  }
}

// ---------------------------------------------------------------- counts + all(counts < 3)
__global__ __launch_bounds__(256) void counts_kernel(const int* __restrict__ pm,
                                                     const int* __restrict__ pred,
                                                     float* __restrict__ out) {
  int b = blockIdx.x, t = threadIdx.x;
  __shared__ int cnt[CC];
  __shared__ int bad;
  for (int c = t; c < CC; c += 256) cnt[c] = 0;
  if (t == 0) bad = 0;
  __syncthreads();
  if (t == 0) atomicAdd(&cnt[pred[b]], 1);
  for (int j = t; j < CC; j += 256) atomicAdd(&cnt[pm[b * CC + j]], 1);
  __syncthreads();
  for (int c = t; c < CC; c += 256) if (cnt[c] >= NSIM) bad = 1;
  __syncthreads();
  if (t == 0) out[b] = bad ? 0.0f : 1.0f;
}

// ---------------------------------------------------------------- launch
extern "C" void kernel_launch(void* const* d_in, const int* in_sizes, int n_in,
                              void* d_out, int out_size, void* d_ws, size_t ws_size,
                              hipStream_t stream) {
  const float* x       = (const float*)d_in[0];
  const float* W_emb   = (const float*)d_in[1];
  const float* b_emb   = (const float*)d_in[2];
  const float* W_fc    = (const float*)d_in[3];
  const float* b_fc    = (const float*)d_in[4];
  const float* anchors = (const float*)d_in[5];
  float* out = (float*)d_out;

  // workspace carve (~10.6 MB), all 16B-aligned
  float* emb    = (float*)d_ws;               // 64*768
  float* logits = emb + BB * DD;              // 64*1000
  float* p      = logits + BB * CC;           // 64*1000
  float* u      = p + BB * CC;                // 64*1000
  float* AE     = u + BB * CC;                // 64*1000
  float* An2    = AE + BB * CC;               // 1024
  float* En2    = An2 + 1024;                 // 64
  int*   pred   = (int*)(En2 + 64);           // 64
  int*   pm     = pred + 64;                  // 64*1000
  short* Bp     = (short*)(pm + BB * CC);     // 64nt*24ks*64*8  = 786432 shorts
  short* Ap     = Bp + 64 * 24 * 64 * 8;      // 786432
  short* Ip     = Ap + 64 * 24 * 64 * 8;      // 48nt*32ks*64*8  = 786432
  short* Xp     = Ip + 48 * 32 * 64 * 8;      // 4*32*64*8       = 65536
  short* Ep     = Xp + 4 * 32 * 64 * 8;       // 4*24*64*8       = 49152
  short* Pp     = Ep + 4 * 24 * 64 * 8;       // 4*32*64*8       = 65536
  unsigned short* Vb = (unsigned short*)(Pp + 4 * 32 * 64 * 8);  // 1024*1024
  short* Vp     = (short*)(Vb + 1024 * 1024); // 64*32*64*8      = 1048576

  hipLaunchKernelGGL(prep_kernel,    dim3(1434), dim3(256), 0, stream,
                     W_fc, anchors, W_emb, x, Bp, Ap, Ip, Xp, An2);
  hipLaunchKernelGGL(embV_kernel,    dim3(268), dim3(256), 0, stream, Bp, Ip, Xp, b_emb, Vb, emb);
  hipLaunchKernelGGL(packmid_kernel, dim3(536), dim3(256), 0, stream, Vb, emb, Vp, Ep);
  hipLaunchKernelGGL(logitsAE_kernel,dim3(64), dim3(64), 0, stream, Ep, Bp, Ap, b_fc, logits, AE);
  hipLaunchKernelGGL(softmax_kernel, dim3(BB), dim3(256), 0, stream, logits, emb, p, Pp, pred, En2);
  hipLaunchKernelGGL(u_kernel,       dim3(64), dim3(64), 0, stream, Pp, Vp, u);
  hipLaunchKernelGGL(scan_kernel,    dim3(BB, 32), dim3(256), 0, stream,
                     logits, u, p, AE, An2, En2, Vb, pm);
  hipLaunchKernelGGL(counts_kernel,  dim3(BB), dim3(256), 0, stream, pm, pred, out);
}

// Round 13
// 87.451 us; speedup vs baseline: 2.4833x; 1.3526x over previous
//
#include <hip/hip_runtime.h>
#include <stdint.h>
#include <stddef.h>

#define BB 64
#define DIN 1024
#define DD 768
#define CC 1000
#define EPSA 0.1f
#define NSIM 3

typedef short  s16x8 __attribute__((ext_vector_type(8)));
typedef float  f32x4 __attribute__((ext_vector_type(4)));

static __device__ __forceinline__ unsigned short f2bf_rne(float x) {
  unsigned u = __float_as_uint(x);
  return (unsigned short)((u + 0x7FFFu + ((u >> 16) & 1u)) >> 16);
}
static __device__ __forceinline__ float bf2f(unsigned short h) {
  return __uint_as_float(((unsigned)h) << 16);
}

// ---------------------------------------------------------------- prep: pack {W_fc,anchors,W_emb,x} to bf16 frags + An2
// frag[nt][ks][lane][reg]: row = nt*16+(lane&15), k = ks*32+(lane>>4)*8+reg
__global__ __launch_bounds__(256) void prep_kernel(const float* __restrict__ W_fc,
                                                   const float* __restrict__ anchors,
                                                   const float* __restrict__ W_emb,
                                                   const float* __restrict__ x,
                                                   short* __restrict__ Bp, short* __restrict__ Ap,
                                                   short* __restrict__ Ip, short* __restrict__ Xp,
                                                   float* __restrict__ An2) {
  const int blk = blockIdx.x, tid = threadIdx.x;
  if (blk < 1184) {
    const float* src; short* dst; int KS, nrow, gid;
    if (blk < 384)       { src = W_fc;    dst = Bp; KS = 24; nrow = CC;  gid = blk * 256 + tid; }
    else if (blk < 768)  { src = anchors; dst = Ap; KS = 24; nrow = CC;  gid = (blk - 384) * 256 + tid; }
    else if (blk < 1152) { src = W_emb;   dst = Ip; KS = 32; nrow = DD;  gid = (blk - 768) * 256 + tid; }
    else                 { src = x;       dst = Xp; KS = 32; nrow = BB;  gid = (blk - 1152) * 256 + tid; }
    int lane = gid & 63;
    int ks   = (gid >> 6) % KS;
    int nt   = gid / (64 * KS);
    int row  = nt * 16 + (lane & 15);
    int k0   = ks * 32 + (lane >> 4) * 8;
    int stride = KS * 32;
    s16x8 v;
    #pragma unroll
    for (int r = 0; r < 8; ++r) {
      float w = (row < nrow) ? src[(size_t)row * stride + k0 + r] : 0.0f;
      v[r] = (short)f2bf_rne(w);
    }
    ((s16x8*)dst)[gid] = v;
  } else {
    int w = tid >> 6, lane = tid & 63;
    int j = (blk - 1184) * 4 + w;          // < 1000
    const float4* ar = (const float4*)(anchors + (size_t)j * DD);
    float an = 0.f;
    for (int k4 = lane; k4 < DD / 4; k4 += 64) {
      float4 a = ar[k4];
      an += a.x*a.x + a.y*a.y + a.z*a.z + a.w*a.w;
    }
    #pragma unroll
    for (int o = 1; o < 64; o <<= 1) an += __shfl_xor(an, o);
    if (lane == 0) An2[j] = an;
  }
}

// ---------------------------------------------------------------- embV: blocks 0..255 -> Vb = bf16(W@W^T); 256..267 -> emb MFMA
__global__ __launch_bounds__(256) void embV_kernel(const short* __restrict__ Bp,
                                                   const short* __restrict__ Ip,
                                                   const short* __restrict__ Xp,
                                                   const float* __restrict__ b_emb,
                                                   unsigned short* __restrict__ Vb,
                                                   float* __restrict__ emb) {
  const int tid = threadIdx.x, w = tid >> 6, lane = tid & 63;
  if (blockIdx.x < 256) {
    const int bx = blockIdx.x & 15, cb = blockIdx.x >> 4;
    const int rnt = bx * 4 + w;
    const s16x8* BH = (const s16x8*)Bp;
    f32x4 acc[4] = {};
    for (int ks = 0; ks < 24; ++ks) {
      s16x8 a = BH[(rnt * 24 + ks) * 64 + lane];
      #pragma unroll
      for (int nf = 0; nf < 4; ++nf)
        acc[nf] = __builtin_amdgcn_mfma_f32_16x16x32_bf16(a, BH[((cb * 4 + nf) * 24 + ks) * 64 + lane], acc[nf], 0, 0, 0);
    }
    const int r0 = rnt * 16 + (lane >> 4) * 4;   // C/D: row=(lane>>4)*4+reg, col=lane&15 [m89]
    const int c0 = cb * 64 + (lane & 15);
    #pragma unroll
    for (int nf = 0; nf < 4; ++nf)
      #pragma unroll
      for (int rr = 0; rr < 4; ++rr)
        Vb[(size_t)(r0 + rr) * 1024 + c0 + nf * 16] = f2bf_rne(acc[nf][rr]);
  } else {
    const int g = blockIdx.x - 256;             // 0..11
    const int nfr = g * 4 + w;                  // 0..47
    const s16x8* XH = (const s16x8*)Xp;
    const s16x8* IH = (const s16x8*)Ip;
    f32x4 acc[4] = {};
    for (int ks = 0; ks < 32; ++ks) {
      s16x8 b = IH[(nfr * 32 + ks) * 64 + lane];
      #pragma unroll
      for (int mt = 0; mt < 4; ++mt)
        acc[mt] = __builtin_amdgcn_mfma_f32_16x16x32_bf16(XH[(mt * 32 + ks) * 64 + lane], b, acc[mt], 0, 0, 0);
    }
    const int d = nfr * 16 + (lane & 15);       // < 768
    const float be = b_emb[d];
    #pragma unroll
    for (int mt = 0; mt < 4; ++mt)
      #pragma unroll
      for (int rr = 0; rr < 4; ++rr)
        emb[(size_t)(mt * 16 + (lane >> 4) * 4 + rr) * DD + d] = acc[mt][rr] + be;
  }
}

// ---------------------------------------------------------------- packmid: blocks 0..511 Vp (from Vb); 512..535 Ep (from emb)
__global__ __launch_bounds__(256) void packmid_kernel(const unsigned short* __restrict__ Vb,
                                                      const float* __restrict__ emb,
                                                      short* __restrict__ Vp,
                                                      short* __restrict__ Ep) {
  const int blk = blockIdx.x, tid = threadIdx.x;
  if (blk < 512) {
    int gid = blk * 256 + tid;                 // 64 nt x 32 ks x 64 = 131072
    int lane = gid & 63, ks = (gid >> 6) % 32, nt = gid / (64 * 32);
    int row = nt * 16 + (lane & 15);
    int k0  = ks * 32 + (lane >> 4) * 8;
    ((s16x8*)Vp)[gid] = *(const s16x8*)(Vb + (size_t)row * 1024 + k0);   // lossless repack
  } else {
    int gid = (blk - 512) * 256 + tid;         // 4 mt x 24 ks x 64 = 6144
    if (gid >= 4 * 24 * 64) return;
    int lane = gid & 63, ks = (gid >> 6) % 24, mt = gid / (64 * 24);
    int row = mt * 16 + (lane & 15);
    int k0  = ks * 32 + (lane >> 4) * 8;
    s16x8 v;
    #pragma unroll
    for (int r = 0; r < 8; ++r) v[r] = (short)f2bf_rne(emb[(size_t)row * DD + k0 + r]);
    ((s16x8*)Ep)[gid] = v;
  }
}

// ---------------------------------------------------------------- logits + AE via MFMA (grid 64 x 4, 1 wave)
__global__ __launch_bounds__(64) void logitsAE_kernel(const short* __restrict__ Ep,
                                                      const short* __restrict__ Bp,
                                                      const short* __restrict__ Ap,
                                                      const float* __restrict__ b_fc,
                                                      float* __restrict__ logits,
                                                      float* __restrict__ AE) {
  const int nfr = blockIdx.x;                  // 0..63
  const int mt  = blockIdx.y;                  // 0..3
  const int lane = threadIdx.x;
  const s16x8* E = (const s16x8*)Ep;
  const s16x8* B = (const s16x8*)Bp;
  const s16x8* A = (const s16x8*)Ap;
  f32x4 accL = {}, accA = {};
  for (int ks = 0; ks < 24; ++ks) {
    s16x8 a  = E[(mt * 24 + ks) * 64 + lane];
    s16x8 bW = B[(nfr * 24 + ks) * 64 + lane];
    s16x8 bA = A[(nfr * 24 + ks) * 64 + lane];
    accL = __builtin_amdgcn_mfma_f32_16x16x32_bf16(a, bW, accL, 0, 0, 0);
    accA = __builtin_amdgcn_mfma_f32_16x16x32_bf16(a, bA, accA, 0, 0, 0);
  }
  const int c = nfr * 16 + (lane & 15);
  if (c < CC) {
    const float bf = b_fc[c];
    #pragma unroll
    for (int rr = 0; rr < 4; ++rr) {
      int b = mt * 16 + (lane >> 4) * 4 + rr;
      logits[b * CC + c] = accL[rr] + bf;
      AE[b * CC + c]     = accA[rr];
    }
  }
}

// ---------------------------------------------------------------- softmax + argmax + En2 + Pp (bf16 frag of p)
__global__ __launch_bounds__(256) void softmax_kernel(const float* __restrict__ logits,
                                                      const float* __restrict__ emb,
                                                      float* __restrict__ p,
                                                      short* __restrict__ Pp,
                                                      int* __restrict__ pred,
                                                      float* __restrict__ En2) {
  int b = blockIdx.x, t = threadIdx.x;
  __shared__ float smax[256];
  __shared__ int   sidx[256];
  __shared__ float ssum[256];
  {
    float pe = 0.f;
    for (int k = t; k < DD; k += 256) { float e = emb[b * DD + k]; pe += e * e; }
    #pragma unroll
    for (int o = 1; o < 64; o <<= 1) pe += __shfl_xor(pe, o);
    __shared__ float se[4];
    if ((t & 63) == 0) se[t >> 6] = pe;
    __syncthreads();
    if (t == 0) En2[b] = se[0] + se[1] + se[2] + se[3];
  }
  float m = -3.402823466e38f; int mi = 0;
  for (int c = t; c < CC; c += 256) {
    float v = logits[b * CC + c];
    if (v > m) { m = v; mi = c; }
  }
  smax[t] = m; sidx[t] = mi;
  __syncthreads();
  for (int o = 128; o > 0; o >>= 1) {
    if (t < o) {
      float v2 = smax[t + o]; int i2 = sidx[t + o];
      if (v2 > smax[t] || (v2 == smax[t] && i2 < sidx[t])) { smax[t] = v2; sidx[t] = i2; }
    }
    __syncthreads();
  }
  float M = smax[0];
  if (t == 0) pred[b] = sidx[0];
  float sum = 0.f;
  for (int c = t; c < CC; c += 256) sum += expf(logits[b * CC + c] - M);
  ssum[t] = sum;
  __syncthreads();
  for (int o = 128; o > 0; o >>= 1) {
    if (t < o) ssum[t] += ssum[t + o];
    __syncthreads();
  }
  float S = ssum[0];
  const int mt = b >> 4, blo = b & 15;
  for (int j = t; j < CC; j += 256) {
    float pj = expf(logits[b * CC + j] - M) / S;
    p[b * CC + j] = pj;
    size_t fi = ((size_t)(mt * 32 + (j >> 5)) * 64 + ((j >> 3) & 3) * 16 + blo) * 8 + (j & 7);
    Pp[fi] = (short)f2bf_rne(pj);
  }
  if (t < 24) {     // zero k-pad 1000..1023
    int j = 1000 + t;
    size_t fi = ((size_t)(mt * 32 + (j >> 5)) * 64 + ((j >> 3) & 3) * 16 + blo) * 8 + (j & 7);
    Pp[fi] = 0;
  }
}

// ---------------------------------------------------------------- u = p @ V via MFMA (grid 64 x 4, 1 wave)
__global__ __launch_bounds__(64) void u_kernel(const short* __restrict__ Pp,
                                               const short* __restrict__ Vp,
                                               float* __restrict__ u) {
  const int nfr = blockIdx.x;                  // 0..63
  const int mt  = blockIdx.y;                  // 0..3
  const int lane = threadIdx.x;
  const s16x8* P = (const s16x8*)Pp;
  const s16x8* V = (const s16x8*)Vp;
  f32x4 acc = {};
  for (int ks = 0; ks < 32; ++ks) {
    s16x8 b = V[(nfr * 32 + ks) * 64 + lane];
    acc = __builtin_amdgcn_mfma_f32_16x16x32_bf16(P[(mt * 32 + ks) * 64 + lane], b, acc, 0, 0, 0);
  }
  const int c = nfr * 16 + (lane & 15);
  if (c < CC) {
    #pragma unroll
    for (int rr = 0; rr < 4; ++rr)
      u[(mt * 16 + (lane >> 4) * 4 + rr) * CC + c] = acc[rr];
  }
}

// ---------------------------------------------------------------- scan: register-resident L/U; V from global; no LDS
// per (b,j): argmax_c of logits[c] + s_j*(u[c] - V[j,c])
__global__ __launch_bounds__(256) void scan_kernel(const float* __restrict__ logits,
                                                   const float* __restrict__ u,
                                                   const float* __restrict__ p,
                                                   const float* __restrict__ AE,
                                                   const float* __restrict__ An2,
                                                   const float* __restrict__ En2,
                                                   const unsigned short* __restrict__ Vb,
                                                   int* __restrict__ pm) {
  const int b = blockIdx.x, jb = blockIdx.y;   // jb < 32
  const int tid = threadIdx.x, w = tid >> 6, lane = tid & 63;
  const int c0 = lane * 16;                    // this lane's 16-c block (covers 0..1023 per wave)

  float L[16], U[16];
  float part = 0.f;                            // p.u partial for Gn2
  #pragma unroll
  for (int g = 0; g < 4; ++g) {
    int cg = c0 + g * 4;
    if (cg + 3 < CC) {
      float4 l4 = *(const float4*)(logits + b * CC + cg);
      float4 u4 = *(const float4*)(u + b * CC + cg);
      float4 p4 = *(const float4*)(p + b * CC + cg);
      L[g*4+0]=l4.x; L[g*4+1]=l4.y; L[g*4+2]=l4.z; L[g*4+3]=l4.w;
      U[g*4+0]=u4.x; U[g*4+1]=u4.y; U[g*4+2]=u4.z; U[g*4+3]=u4.w;
      part += p4.x*u4.x + p4.y*u4.y + p4.z*u4.z + p4.w*u4.w;
    } else {
      #pragma unroll
      for (int i2 = 0; i2 < 4; ++i2) {
        int c = cg + i2;
        bool ok = (c < CC);
        float lv = ok ? logits[b * CC + c] : -3.402823466e38f;
        float uv = ok ? u[b * CC + c] : 0.f;
        float pv = ok ? p[b * CC + c] : 0.f;
        L[g*4+i2] = lv; U[g*4+i2] = uv;
        part += pv * uv;
      }
    }
  }
  #pragma unroll
  for (int o = 1; o < 64; o <<= 1) part += __shfl_xor(part, o);
  const float gn2b = part;                     // each wave spans all c -> full sum
  const float en2 = En2[b];

  for (int jj = 0; jj < 8; ++jj) {
    int j = jb * 32 + w * 8 + jj;
    if (j >= CC) break;                        // uniform per wave
    float zn2 = An2[j] - 2.0f * AE[b * CC + j] + en2;
    float gn2 = gn2b - 2.0f * u[b * CC + j] + bf2f(Vb[(size_t)j * 1024 + j]);
    float sj = (EPSA * sqrtf(zn2)) / sqrtf(gn2);
    const s16x8* Vr = (const s16x8*)(Vb + (size_t)j * 1024);
    s16x8 v8a = Vr[lane * 2];
    s16x8 v8b = Vr[lane * 2 + 1];
    float best = -3.402823466e38f; int bi = 0;
    #pragma unroll
    for (int i = 0; i < 8; ++i) {
      float v = bf2f((unsigned short)v8a[i]);
      float val = L[i] + sj * (U[i] - v);
      if (val > best) { best = val; bi = c0 + i; }
    }
    #pragma unroll
    for (int i = 0; i < 8; ++i) {
      float v = bf2f((unsigned short)v8b[i]);
      float val = L[8 + i] + sj * (U[8 + i] - v);
      if (val > best) { best = val; bi = c0 + 8 + i; }
    }
    #pragma unroll
    for (int o = 1; o < 64; o <<= 1) {
      float ov = __shfl_xor(best, o);
      int   oi = __shfl_xor(bi, o);
      if (ov > best || (ov == best && oi < bi)) { best = ov; bi = oi; }
    }
    if (lane == 0) pm[b * CC + j] = bi;
  }
}

// ---------------------------------------------------------------- counts + all(counts < 3)
__global__ __launch_bounds__(256) void counts_kernel(const int* __restrict__ pm,
                                                     const int* __restrict__ pred,
                                                     float* __restrict__ out) {
  int b = blockIdx.x, t = threadIdx.x;
  __shared__ int cnt[CC];
  __shared__ int bad;
  for (int c = t; c < CC; c += 256) cnt[c] = 0;
  if (t == 0) bad = 0;
  __syncthreads();
  if (t == 0) atomicAdd(&cnt[pred[b]], 1);
  for (int j = t; j < CC; j += 256) atomicAdd(&cnt[pm[b * CC + j]], 1);
  __syncthreads();
  for (int c = t; c < CC; c += 256) if (cnt[c] >= NSIM) bad = 1;
  __syncthreads();
  if (t == 0) out[b] = bad ? 0.0f : 1.0f;
}

// ---------------------------------------------------------------- launch
extern "C" void kernel_launch(void* const* d_in, const int* in_sizes, int n_in,
                              void* d_out, int out_size, void* d_ws, size_t ws_size,
                              hipStream_t stream) {
  const float* x       = (const float*)d_in[0];
  const float* W_emb   = (const float*)d_in[1];
  const float* b_emb   = (const float*)d_in[2];
  const float* W_fc    = (const float*)d_in[3];
  const float* b_fc    = (const float*)d_in[4];
  const float* anchors = (const float*)d_in[5];
  float* out = (float*)d_out;

  // workspace carve (~10.6 MB), all 16B-aligned
  float* emb    = (float*)d_ws;               // 64*768
  float* logits = emb + BB * DD;              // 64*1000
  float* p      = logits + BB * CC;           // 64*1000
  float* u      = p + BB * CC;                // 64*1000
  float* AE     = u + BB * CC;                // 64*1000
  float* An2    = AE + BB * CC;               // 1024
  float* En2    = An2 + 1024;                 // 64
  int*   pred   = (int*)(En2 + 64);           // 64
  int*   pm     = pred + 64;                  // 64*1000
  short* Bp     = (short*)(pm + BB * CC);     // 786432 shorts
  short* Ap     = Bp + 64 * 24 * 64 * 8;      // 786432
  short* Ip     = Ap + 64 * 24 * 64 * 8;      // 786432
  short* Xp     = Ip + 48 * 32 * 64 * 8;      // 65536
  short* Ep     = Xp + 4 * 32 * 64 * 8;       // 49152
  short* Pp     = Ep + 4 * 24 * 64 * 8;       // 65536
  unsigned short* Vb = (unsigned short*)(Pp + 4 * 32 * 64 * 8);  // 1024*1024
  short* Vp     = (short*)(Vb + 1024 * 1024); // 1048576

  hipLaunchKernelGGL(prep_kernel,    dim3(1434), dim3(256), 0, stream,
                     W_fc, anchors, W_emb, x, Bp, Ap, Ip, Xp, An2);
  hipLaunchKernelGGL(embV_kernel,    dim3(268), dim3(256), 0, stream, Bp, Ip, Xp, b_emb, Vb, emb);
  hipLaunchKernelGGL(packmid_kernel, dim3(536), dim3(256), 0, stream, Vb, emb, Vp, Ep);
  hipLaunchKernelGGL(logitsAE_kernel,dim3(64, 4), dim3(64), 0, stream, Ep, Bp, Ap, b_fc, logits, AE);
  hipLaunchKernelGGL(softmax_kernel, dim3(BB), dim3(256), 0, stream, logits, emb, p, Pp, pred, En2);
  hipLaunchKernelGGL(u_kernel,       dim3(64, 4), dim3(64), 0, stream, Pp, Vp, u);
  hipLaunchKernelGGL(scan_kernel,    dim3(BB, 32), dim3(256), 0, stream,
                     logits, u, p, AE, An2, En2, Vb, pm);
  hipLaunchKernelGGL(counts_kernel,  dim3(BB), dim3(256), 0, stream, pm, pred, out);
}

// Round 14
// 86.270 us; speedup vs baseline: 2.5173x; 1.0137x over previous
//
#include <hip/hip_runtime.h>
#include <stdint.h>
#include <stddef.h>

#define BB 64
#define DIN 1024
#define DD 768
#define CC 1000
#define EPSA 0.1f
#define NSIM 3

typedef short  s16x8 __attribute__((ext_vector_type(8)));
typedef float  f32x4 __attribute__((ext_vector_type(4)));

static __device__ __forceinline__ unsigned short f2bf_rne(float x) {
  unsigned u = __float_as_uint(x);
  return (unsigned short)((u + 0x7FFFu + ((u >> 16) & 1u)) >> 16);
}
static __device__ __forceinline__ float bf2f(unsigned short h) {
  return __uint_as_float(((unsigned)h) << 16);
}

// ---------------------------------------------------------------- prep: pack {W_fc,anchors,W_emb,x} to bf16 frags + An2
// frag[nt][ks][lane][reg]: row = nt*16+(lane&15), k = ks*32+(lane>>4)*8+reg
__global__ __launch_bounds__(256) void prep_kernel(const float* __restrict__ W_fc,
                                                   const float* __restrict__ anchors,
                                                   const float* __restrict__ W_emb,
                                                   const float* __restrict__ x,
                                                   short* __restrict__ Bp, short* __restrict__ Ap,
                                                   short* __restrict__ Ip, short* __restrict__ Xp,
                                                   float* __restrict__ An2) {
  const int blk = blockIdx.x, tid = threadIdx.x;
  if (blk < 1184) {
    const float* src; short* dst; int KS, nrow, gid;
    if (blk < 384)       { src = W_fc;    dst = Bp; KS = 24; nrow = CC;  gid = blk * 256 + tid; }
    else if (blk < 768)  { src = anchors; dst = Ap; KS = 24; nrow = CC;  gid = (blk - 384) * 256 + tid; }
    else if (blk < 1152) { src = W_emb;   dst = Ip; KS = 32; nrow = DD;  gid = (blk - 768) * 256 + tid; }
    else                 { src = x;       dst = Xp; KS = 32; nrow = BB;  gid = (blk - 1152) * 256 + tid; }
    int lane = gid & 63;
    int ks   = (gid >> 6) % KS;
    int nt   = gid / (64 * KS);
    int row  = nt * 16 + (lane & 15);
    int k0   = ks * 32 + (lane >> 4) * 8;
    int stride = KS * 32;
    s16x8 v;
    #pragma unroll
    for (int r = 0; r < 8; ++r) {
      float w = (row < nrow) ? src[(size_t)row * stride + k0 + r] : 0.0f;
      v[r] = (short)f2bf_rne(w);
    }
    ((s16x8*)dst)[gid] = v;
  } else {
    int w = tid >> 6, lane = tid & 63;
    int j = (blk - 1184) * 4 + w;          // < 1000
    const float4* ar = (const float4*)(anchors + (size_t)j * DD);
    float an = 0.f;
    for (int k4 = lane; k4 < DD / 4; k4 += 64) {
      float4 a = ar[k4];
      an += a.x*a.x + a.y*a.y + a.z*a.z + a.w*a.w;
    }
    #pragma unroll
    for (int o = 1; o < 64; o <<= 1) an += __shfl_xor(an, o);
    if (lane == 0) An2[j] = an;
  }
}

// ---------------------------------------------------------------- embV: blocks 0..255 -> Vb = bf16(W@W^T); 256..267 -> emb MFMA
__global__ __launch_bounds__(256) void embV_kernel(const short* __restrict__ Bp,
                                                   const short* __restrict__ Ip,
                                                   const short* __restrict__ Xp,
                                                   const float* __restrict__ b_emb,
                                                   unsigned short* __restrict__ Vb,
                                                   float* __restrict__ emb) {
  const int tid = threadIdx.x, w = tid >> 6, lane = tid & 63;
  if (blockIdx.x < 256) {
    const int bx = blockIdx.x & 15, cb = blockIdx.x >> 4;
    const int rnt = bx * 4 + w;
    const s16x8* BH = (const s16x8*)Bp;
    f32x4 acc[4] = {};
    for (int ks = 0; ks < 24; ++ks) {
      s16x8 a = BH[(rnt * 24 + ks) * 64 + lane];
      #pragma unroll
      for (int nf = 0; nf < 4; ++nf)
        acc[nf] = __builtin_amdgcn_mfma_f32_16x16x32_bf16(a, BH[((cb * 4 + nf) * 24 + ks) * 64 + lane], acc[nf], 0, 0, 0);
    }
    const int r0 = rnt * 16 + (lane >> 4) * 4;   // C/D: row=(lane>>4)*4+reg, col=lane&15 [m89]
    const int c0 = cb * 64 + (lane & 15);
    #pragma unroll
    for (int nf = 0; nf < 4; ++nf)
      #pragma unroll
      for (int rr = 0; rr < 4; ++rr)
        Vb[(size_t)(r0 + rr) * 1024 + c0 + nf * 16] = f2bf_rne(acc[nf][rr]);
  } else {
    const int g = blockIdx.x - 256;             // 0..11
    const int nfr = g * 4 + w;                  // 0..47
    const s16x8* XH = (const s16x8*)Xp;
    const s16x8* IH = (const s16x8*)Ip;
    f32x4 acc[4] = {};
    for (int ks = 0; ks < 32; ++ks) {
      s16x8 b = IH[(nfr * 32 + ks) * 64 + lane];
      #pragma unroll
      for (int mt = 0; mt < 4; ++mt)
        acc[mt] = __builtin_amdgcn_mfma_f32_16x16x32_bf16(XH[(mt * 32 + ks) * 64 + lane], b, acc[mt], 0, 0, 0);
    }
    const int d = nfr * 16 + (lane & 15);       // < 768
    const float be = b_emb[d];
    #pragma unroll
    for (int mt = 0; mt < 4; ++mt)
      #pragma unroll
      for (int rr = 0; rr < 4; ++rr)
        emb[(size_t)(mt * 16 + (lane >> 4) * 4 + rr) * DD + d] = acc[mt][rr] + be;
  }
}

// ---------------------------------------------------------------- packmid: blocks 0..511 Vp (from Vb); 512..535 Ep (from emb)
__global__ __launch_bounds__(256) void packmid_kernel(const unsigned short* __restrict__ Vb,
                                                      const float* __restrict__ emb,
                                                      short* __restrict__ Vp,
                                                      short* __restrict__ Ep) {
  const int blk = blockIdx.x, tid = threadIdx.x;
  if (blk < 512) {
    int gid = blk * 256 + tid;                 // 64 nt x 32 ks x 64 = 131072
    int lane = gid & 63, ks = (gid >> 6) % 32, nt = gid / (64 * 32);
    int row = nt * 16 + (lane & 15);
    int k0  = ks * 32 + (lane >> 4) * 8;
    ((s16x8*)Vp)[gid] = *(const s16x8*)(Vb + (size_t)row * 1024 + k0);   // lossless repack
  } else {
    int gid = (blk - 512) * 256 + tid;         // 4 mt x 24 ks x 64 = 6144
    if (gid >= 4 * 24 * 64) return;
    int lane = gid & 63, ks = (gid >> 6) % 24, mt = gid / (64 * 24);
    int row = mt * 16 + (lane & 15);
    int k0  = ks * 32 + (lane >> 4) * 8;
    s16x8 v;
    #pragma unroll
    for (int r = 0; r < 8; ++r) v[r] = (short)f2bf_rne(emb[(size_t)row * DD + k0 + r]);
    ((s16x8*)Ep)[gid] = v;
  }
}

// ---------------------------------------------------------------- logits + AE via MFMA (grid 64 x 4, 1 wave)
__global__ __launch_bounds__(64) void logitsAE_kernel(const short* __restrict__ Ep,
                                                      const short* __restrict__ Bp,
                                                      const short* __restrict__ Ap,
                                                      const float* __restrict__ b_fc,
                                                      float* __restrict__ logits,
                                                      float* __restrict__ AE) {
  const int nfr = blockIdx.x;                  // 0..63
  const int mt  = blockIdx.y;                  // 0..3
  const int lane = threadIdx.x;
  const s16x8* E = (const s16x8*)Ep;
  const s16x8* B = (const s16x8*)Bp;
  const s16x8* A = (const s16x8*)Ap;
  f32x4 accL = {}, accA = {};
  for (int ks = 0; ks < 24; ++ks) {
    s16x8 a  = E[(mt * 24 + ks) * 64 + lane];
    s16x8 bW = B[(nfr * 24 + ks) * 64 + lane];
    s16x8 bA = A[(nfr * 24 + ks) * 64 + lane];
    accL = __builtin_amdgcn_mfma_f32_16x16x32_bf16(a, bW, accL, 0, 0, 0);
    accA = __builtin_amdgcn_mfma_f32_16x16x32_bf16(a, bA, accA, 0, 0, 0);
  }
  const int c = nfr * 16 + (lane & 15);
  if (c < CC) {
    const float bf = b_fc[c];
    #pragma unroll
    for (int rr = 0; rr < 4; ++rr) {
      int b = mt * 16 + (lane >> 4) * 4 + rr;
      logits[b * CC + c] = accL[rr] + bf;
      AE[b * CC + c]     = accA[rr];
    }
  }
}

// ---------------------------------------------------------------- softmax + argmax + En2 + Pp (bf16 frag of p)
__global__ __launch_bounds__(256) void softmax_kernel(const float* __restrict__ logits,
                                                      const float* __restrict__ emb,
                                                      float* __restrict__ p,
                                                      short* __restrict__ Pp,
                                                      int* __restrict__ pred,
                                                      float* __restrict__ En2) {
  int b = blockIdx.x, t = threadIdx.x;
  __shared__ float smax[256];
  __shared__ int   sidx[256];
  __shared__ float ssum[256];
  {
    float pe = 0.f;
    for (int k = t; k < DD; k += 256) { float e = emb[b * DD + k]; pe += e * e; }
    #pragma unroll
    for (int o = 1; o < 64; o <<= 1) pe += __shfl_xor(pe, o);
    __shared__ float se[4];
    if ((t & 63) == 0) se[t >> 6] = pe;
    __syncthreads();
    if (t == 0) En2[b] = se[0] + se[1] + se[2] + se[3];
  }
  float m = -3.402823466e38f; int mi = 0;
  for (int c = t; c < CC; c += 256) {
    float v = logits[b * CC + c];
    if (v > m) { m = v; mi = c; }
  }
  smax[t] = m; sidx[t] = mi;
  __syncthreads();
  for (int o = 128; o > 0; o >>= 1) {
    if (t < o) {
      float v2 = smax[t + o]; int i2 = sidx[t + o];
      if (v2 > smax[t] || (v2 == smax[t] && i2 < sidx[t])) { smax[t] = v2; sidx[t] = i2; }
    }
    __syncthreads();
  }
  float M = smax[0];
  if (t == 0) pred[b] = sidx[0];
  float sum = 0.f;
  for (int c = t; c < CC; c += 256) sum += expf(logits[b * CC + c] - M);
  ssum[t] = sum;
  __syncthreads();
  for (int o = 128; o > 0; o >>= 1) {
    if (t < o) ssum[t] += ssum[t + o];
    __syncthreads();
  }
  float S = ssum[0];
  const int mt = b >> 4, blo = b & 15;
  for (int j = t; j < CC; j += 256) {
    float pj = expf(logits[b * CC + j] - M) / S;
    p[b * CC + j] = pj;
    size_t fi = ((size_t)(mt * 32 + (j >> 5)) * 64 + ((j >> 3) & 3) * 16 + blo) * 8 + (j & 7);
    Pp[fi] = (short)f2bf_rne(pj);
  }
  if (t < 24) {     // zero k-pad 1000..1023
    int j = 1000 + t;
    size_t fi = ((size_t)(mt * 32 + (j >> 5)) * 64 + ((j >> 3) & 3) * 16 + blo) * 8 + (j & 7);
    Pp[fi] = 0;
  }
}

// ---------------------------------------------------------------- u = p @ V via MFMA (grid 64 x 4, 1 wave)
__global__ __launch_bounds__(64) void u_kernel(const short* __restrict__ Pp,
                                               const short* __restrict__ Vp,
                                               float* __restrict__ u) {
  const int nfr = blockIdx.x;                  // 0..63
  const int mt  = blockIdx.y;                  // 0..3
  const int lane = threadIdx.x;
  const s16x8* P = (const s16x8*)Pp;
  const s16x8* V = (const s16x8*)Vp;
  f32x4 acc = {};
  for (int ks = 0; ks < 32; ++ks) {
    s16x8 b = V[(nfr * 32 + ks) * 64 + lane];
    acc = __builtin_amdgcn_mfma_f32_16x16x32_bf16(P[(mt * 32 + ks) * 64 + lane], b, acc, 0, 0, 0);
  }
  const int c = nfr * 16 + (lane & 15);
  if (c < CC) {
    #pragma unroll
    for (int rr = 0; rr < 4; ++rr)
      u[(mt * 16 + (lane >> 4) * 4 + rr) * CC + c] = acc[rr];
  }
}

// ---------------------------------------------------------------- scan: register-resident L/U; 4 j per wave, batched ILP
// per (b,j): argmax_c of logits[c] + s_j*(u[c] - V[j,c])
__global__ __launch_bounds__(256) void scan_kernel(const float* __restrict__ logits,
                                                   const float* __restrict__ u,
                                                   const float* __restrict__ p,
                                                   const float* __restrict__ AE,
                                                   const float* __restrict__ An2,
                                                   const float* __restrict__ En2,
                                                   const unsigned short* __restrict__ Vb,
                                                   int* __restrict__ pm) {
  const int b = blockIdx.x, jb = blockIdx.y;   // jb < 64
  const int tid = threadIdx.x, w = tid >> 6, lane = tid & 63;
  const int c0 = lane * 16;                    // this lane's 16-c block (covers 0..1023 per wave)
  const int jbase = jb * 16 + w * 4;           // 4 j per wave

  float L[16], U[16];
  float part = 0.f;                            // p.u partial for Gn2
  #pragma unroll
  for (int g = 0; g < 4; ++g) {
    int cg = c0 + g * 4;
    if (cg + 3 < CC) {
      float4 l4 = *(const float4*)(logits + b * CC + cg);
      float4 u4 = *(const float4*)(u + b * CC + cg);
      float4 p4 = *(const float4*)(p + b * CC + cg);
      L[g*4+0]=l4.x; L[g*4+1]=l4.y; L[g*4+2]=l4.z; L[g*4+3]=l4.w;
      U[g*4+0]=u4.x; U[g*4+1]=u4.y; U[g*4+2]=u4.z; U[g*4+3]=u4.w;
      part += p4.x*u4.x + p4.y*u4.y + p4.z*u4.z + p4.w*u4.w;
    } else {
      #pragma unroll
      for (int i2 = 0; i2 < 4; ++i2) {
        int c = cg + i2;
        bool ok = (c < CC);
        float lv = ok ? logits[b * CC + c] : -3.402823466e38f;
        float uv = ok ? u[b * CC + c] : 0.f;
        float pv = ok ? p[b * CC + c] : 0.f;
        L[g*4+i2] = lv; U[g*4+i2] = uv;
        part += pv * uv;
      }
    }
  }
  #pragma unroll
  for (int o = 1; o < 64; o <<= 1) part += __shfl_xor(part, o);
  const float gn2b = part;
  const float en2 = En2[b];

  // phase 1: issue all V-row loads (4 j's) — latency overlapped
  int jr[4];
  s16x8 va[4], vbh[4];
  #pragma unroll
  for (int jj = 0; jj < 4; ++jj) {
    int j = jbase + jj;
    jr[jj] = (j < CC) ? j : (CC - 1);
    const s16x8* Vr = (const s16x8*)(Vb + (size_t)jr[jj] * 1024);
    va[jj]  = Vr[lane * 2];
    vbh[jj] = Vr[lane * 2 + 1];
  }
  // phase 2: s_j for all 4 (independent)
  float sj[4];
  #pragma unroll
  for (int jj = 0; jj < 4; ++jj) {
    float zn2 = An2[jr[jj]] - 2.0f * AE[b * CC + jr[jj]] + en2;
    float gn2 = gn2b - 2.0f * u[b * CC + jr[jj]] + bf2f(Vb[(size_t)jr[jj] * 1024 + jr[jj]]);
    sj[jj] = (EPSA * sqrtf(zn2)) / sqrtf(gn2);
  }
  // phase 3: local 16-c scans (independent VALU)
  float best[4]; int bi[4];
  #pragma unroll
  for (int jj = 0; jj < 4; ++jj) {
    float bst = -3.402823466e38f; int bix = 0;
    #pragma unroll
    for (int i = 0; i < 8; ++i) {
      float val = L[i] + sj[jj] * (U[i] - bf2f((unsigned short)va[jj][i]));
      if (val > bst) { bst = val; bix = c0 + i; }
    }
    #pragma unroll
    for (int i = 0; i < 8; ++i) {
      float val = L[8 + i] + sj[jj] * (U[8 + i] - bf2f((unsigned short)vbh[jj][i]));
      if (val > bst) { bst = val; bix = c0 + 8 + i; }
    }
    best[jj] = bst; bi[jj] = bix;
  }
  // phase 4: interleaved reductions (8 independent bpermutes per step)
  #pragma unroll
  for (int o = 1; o < 64; o <<= 1) {
    float ov[4]; int oi[4];
    #pragma unroll
    for (int jj = 0; jj < 4; ++jj) { ov[jj] = __shfl_xor(best[jj], o); oi[jj] = __shfl_xor(bi[jj], o); }
    #pragma unroll
    for (int jj = 0; jj < 4; ++jj) {
      if (ov[jj] > best[jj] || (ov[jj] == best[jj] && oi[jj] < bi[jj])) { best[jj] = ov[jj]; bi[jj] = oi[jj]; }
    }
  }
  if (lane == 0) {
    #pragma unroll
    for (int jj = 0; jj < 4; ++jj) {
      int j = jbase + jj;
      if (j < CC) pm[b * CC + j] = bi[jj];
    }
  }
}

// ---------------------------------------------------------------- counts + all(counts < 3)
__global__ __launch_bounds__(256) void counts_kernel(const int* __restrict__ pm,
                                                     const int* __restrict__ pred,
                                                     float* __restrict__ out) {
  int b = blockIdx.x, t = threadIdx.x;
  __shared__ int cnt[CC];
  __shared__ int bad;
  for (int c = t; c < CC; c += 256) cnt[c] = 0;
  if (t == 0) bad = 0;
  __syncthreads();
  if (t == 0) atomicAdd(&cnt[pred[b]], 1);
  for (int j = t; j < CC; j += 256) atomicAdd(&cnt[pm[b * CC + j]], 1);
  __syncthreads();
  for (int c = t; c < CC; c += 256) if (cnt[c] >= NSIM) bad = 1;
  __syncthreads();
  if (t == 0) out[b] = bad ? 0.0f : 1.0f;
}

// ---------------------------------------------------------------- launch
extern "C" void kernel_launch(void* const* d_in, const int* in_sizes, int n_in,
                              void* d_out, int out_size, void* d_ws, size_t ws_size,
                              hipStream_t stream) {
  const float* x       = (const float*)d_in[0];
  const float* W_emb   = (const float*)d_in[1];
  const float* b_emb   = (const float*)d_in[2];
  const float* W_fc    = (const float*)d_in[3];
  const float* b_fc    = (const float*)d_in[4];
  const float* anchors = (const float*)d_in[5];
  float* out = (float*)d_out;

  // workspace carve (~10.6 MB), all 16B-aligned
  float* emb    = (float*)d_ws;               // 64*768
  float* logits = emb + BB * DD;              // 64*1000
  float* p      = logits + BB * CC;           // 64*1000
  float* u      = p + BB * CC;                // 64*1000
  float* AE     = u + BB * CC;                // 64*1000
  float* An2    = AE + BB * CC;               // 1024
  float* En2    = An2 + 1024;                 // 64
  int*   pred   = (int*)(En2 + 64);           // 64
  int*   pm     = pred + 64;                  // 64*1000
  short* Bp     = (short*)(pm + BB * CC);     // 786432 shorts
  short* Ap     = Bp + 64 * 24 * 64 * 8;      // 786432
  short* Ip     = Ap + 64 * 24 * 64 * 8;      // 786432
  short* Xp     = Ip + 48 * 32 * 64 * 8;      // 65536
  short* Ep     = Xp + 4 * 32 * 64 * 8;       // 49152
  short* Pp     = Ep + 4 * 24 * 64 * 8;       // 65536
  unsigned short* Vb = (unsigned short*)(Pp + 4 * 32 * 64 * 8);  // 1024*1024
  short* Vp     = (short*)(Vb + 1024 * 1024); // 1048576

  hipLaunchKernelGGL(prep_kernel,    dim3(1434), dim3(256), 0, stream,
                     W_fc, anchors, W_emb, x, Bp, Ap, Ip, Xp, An2);
  hipLaunchKernelGGL(embV_kernel,    dim3(268), dim3(256), 0, stream, Bp, Ip, Xp, b_emb, Vb, emb);
  hipLaunchKernelGGL(packmid_kernel, dim3(536), dim3(256), 0, stream, Vb, emb, Vp, Ep);
  hipLaunchKernelGGL(logitsAE_kernel,dim3(64, 4), dim3(64), 0, stream, Ep, Bp, Ap, b_fc, logits, AE);
  hipLaunchKernelGGL(softmax_kernel, dim3(BB), dim3(256), 0, stream, logits, emb, p, Pp, pred, En2);
  hipLaunchKernelGGL(u_kernel,       dim3(64, 4), dim3(64), 0, stream, Pp, Vp, u);
  hipLaunchKernelGGL(scan_kernel,    dim3(BB, 64), dim3(256), 0, stream,
                     logits, u, p, AE, An2, En2, Vb, pm);
  hipLaunchKernelGGL(counts_kernel,  dim3(BB), dim3(256), 0, stream, pm, pred, out);
}

// Round 16
// 73.194 us; speedup vs baseline: 2.9670x; 1.1787x over previous
//
#include <hip/hip_runtime.h>
#include <stdint.h>
#include <stddef.h>

#define BB 64
#define DIN 1024
#define DD 768
#define CC 1000
#define EPSA 0.1f
#define NSIM 3

typedef short  s16x8 __attribute__((ext_vector_type(8)));
typedef float  f32x4 __attribute__((ext_vector_type(4)));

static __device__ __forceinline__ unsigned short f2bf_rne(float x) {
  unsigned u = __float_as_uint(x);
  return (unsigned short)((u + 0x7FFFu + ((u >> 16) & 1u)) >> 16);
}
static __device__ __forceinline__ float bf2f(unsigned short h) {
  return __uint_as_float(((unsigned)h) << 16);
}

// ---------------------------------------------------------------- prep: pack {W_fc,anchors,W_emb,x} to bf16 frags + An2
// frag[nt][ks][lane][reg]: row = nt*16+(lane&15), k = ks*32+(lane>>4)*8+reg
__global__ __launch_bounds__(256) void prep_kernel(const float* __restrict__ W_fc,
                                                   const float* __restrict__ anchors,
                                                   const float* __restrict__ W_emb,
                                                   const float* __restrict__ x,
                                                   short* __restrict__ Bp, short* __restrict__ Ap,
                                                   short* __restrict__ Ip, short* __restrict__ Xp,
                                                   float* __restrict__ An2) {
  const int blk = blockIdx.x, tid = threadIdx.x;
  if (blk < 1184) {
    const float* src; short* dst; int KS, nrow, gid;
    if (blk < 384)       { src = W_fc;    dst = Bp; KS = 24; nrow = CC;  gid = blk * 256 + tid; }
    else if (blk < 768)  { src = anchors; dst = Ap; KS = 24; nrow = CC;  gid = (blk - 384) * 256 + tid; }
    else if (blk < 1152) { src = W_emb;   dst = Ip; KS = 32; nrow = DD;  gid = (blk - 768) * 256 + tid; }
    else                 { src = x;       dst = Xp; KS = 32; nrow = BB;  gid = (blk - 1152) * 256 + tid; }
    int lane = gid & 63;
    int ks   = (gid >> 6) % KS;
    int nt   = gid / (64 * KS);
    int row  = nt * 16 + (lane & 15);
    int k0   = ks * 32 + (lane >> 4) * 8;
    int stride = KS * 32;
    s16x8 v;
    #pragma unroll
    for (int r = 0; r < 8; ++r) {
      float w = (row < nrow) ? src[(size_t)row * stride + k0 + r] : 0.0f;
      v[r] = (short)f2bf_rne(w);
    }
    ((s16x8*)dst)[gid] = v;
  } else {
    int w = tid >> 6, lane = tid & 63;
    int j = (blk - 1184) * 4 + w;          // < 1000
    const float4* ar = (const float4*)(anchors + (size_t)j * DD);
    float an = 0.f;
    for (int k4 = lane; k4 < DD / 4; k4 += 64) {
      float4 a = ar[k4];
      an += a.x*a.x + a.y*a.y + a.z*a.z + a.w*a.w;
    }
    #pragma unroll
    for (int o = 1; o < 64; o <<= 1) an += __shfl_xor(an, o);
    if (lane == 0) An2[j] = an;
  }
}

// ---------------------------------------------------------------- embV: blocks 0..255 -> Vb = bf16(W@W^T); 256..267 -> emb MFMA
__global__ __launch_bounds__(256) void embV_kernel(const short* __restrict__ Bp,
                                                   const short* __restrict__ Ip,
                                                   const short* __restrict__ Xp,
                                                   const float* __restrict__ b_emb,
                                                   unsigned short* __restrict__ Vb,
                                                   float* __restrict__ emb) {
  const int tid = threadIdx.x, w = tid >> 6, lane = tid & 63;
  if (blockIdx.x < 256) {
    const int bx = blockIdx.x & 15, cb = blockIdx.x >> 4;
    const int rnt = bx * 4 + w;
    const s16x8* BH = (const s16x8*)Bp;
    f32x4 acc[4] = {};
    for (int ks = 0; ks < 24; ++ks) {
      s16x8 a = BH[(rnt * 24 + ks) * 64 + lane];
      #pragma unroll
      for (int nf = 0; nf < 4; ++nf)
        acc[nf] = __builtin_amdgcn_mfma_f32_16x16x32_bf16(a, BH[((cb * 4 + nf) * 24 + ks) * 64 + lane], acc[nf], 0, 0, 0);
    }
    const int r0 = rnt * 16 + (lane >> 4) * 4;   // C/D: row=(lane>>4)*4+reg, col=lane&15 [m89]
    const int c0 = cb * 64 + (lane & 15);
    #pragma unroll
    for (int nf = 0; nf < 4; ++nf)
      #pragma unroll
      for (int rr = 0; rr < 4; ++rr)
        Vb[(size_t)(r0 + rr) * 1024 + c0 + nf * 16] = f2bf_rne(acc[nf][rr]);
  } else {
    const int g = blockIdx.x - 256;             // 0..11
    const int nfr = g * 4 + w;                  // 0..47
    const s16x8* XH = (const s16x8*)Xp;
    const s16x8* IH = (const s16x8*)Ip;
    f32x4 acc[4] = {};
    for (int ks = 0; ks < 32; ++ks) {
      s16x8 b = IH[(nfr * 32 + ks) * 64 + lane];
      #pragma unroll
      for (int mt = 0; mt < 4; ++mt)
        acc[mt] = __builtin_amdgcn_mfma_f32_16x16x32_bf16(XH[(mt * 32 + ks) * 64 + lane], b, acc[mt], 0, 0, 0);
    }
    const int d = nfr * 16 + (lane & 15);       // < 768
    const float be = b_emb[d];
    #pragma unroll
    for (int mt = 0; mt < 4; ++mt)
      #pragma unroll
      for (int rr = 0; rr < 4; ++rr)
        emb[(size_t)(mt * 16 + (lane >> 4) * 4 + rr) * DD + d] = acc[mt][rr] + be;
  }
}

// ---------------------------------------------------------------- packmid: blocks 0..511 Vp (from Vb); 512..535 Ep (from emb)
__global__ __launch_bounds__(256) void packmid_kernel(const unsigned short* __restrict__ Vb,
                                                      const float* __restrict__ emb,
                                                      short* __restrict__ Vp,
                                                      short* __restrict__ Ep) {
  const int blk = blockIdx.x, tid = threadIdx.x;
  if (blk < 512) {
    int gid = blk * 256 + tid;                 // 64 nt x 32 ks x 64 = 131072
    int lane = gid & 63, ks = (gid >> 6) % 32, nt = gid / (64 * 32);
    int row = nt * 16 + (lane & 15);
    int k0  = ks * 32 + (lane >> 4) * 8;
    ((s16x8*)Vp)[gid] = *(const s16x8*)(Vb + (size_t)row * 1024 + k0);   // lossless repack
  } else {
    int gid = (blk - 512) * 256 + tid;         // 4 mt x 24 ks x 64 = 6144
    if (gid >= 4 * 24 * 64) return;
    int lane = gid & 63, ks = (gid >> 6) % 24, mt = gid / (64 * 24);
    int row = mt * 16 + (lane & 15);
    int k0  = ks * 32 + (lane >> 4) * 8;
    s16x8 v;
    #pragma unroll
    for (int r = 0; r < 8; ++r) v[r] = (short)f2bf_rne(emb[(size_t)row * DD + k0 + r]);
    ((s16x8*)Ep)[gid] = v;
  }
}

// ---------------------------------------------------------------- logits + AE via MFMA (grid 64 x 4, 1 wave)
__global__ __launch_bounds__(64) void logitsAE_kernel(const short* __restrict__ Ep,
                                                      const short* __restrict__ Bp,
                                                      const short* __restrict__ Ap,
                                                      const float* __restrict__ b_fc,
                                                      float* __restrict__ logits,
                                                      float* __restrict__ AE) {
  const int nfr = blockIdx.x;                  // 0..63
  const int mt  = blockIdx.y;                  // 0..3
  const int lane = threadIdx.x;
  const s16x8* E = (const s16x8*)Ep;
  const s16x8* B = (const s16x8*)Bp;
  const s16x8* A = (const s16x8*)Ap;
  f32x4 accL = {}, accA = {};
  for (int ks = 0; ks < 24; ++ks) {
    s16x8 a  = E[(mt * 24 + ks) * 64 + lane];
    s16x8 bW = B[(nfr * 24 + ks) * 64 + lane];
    s16x8 bA = A[(nfr * 24 + ks) * 64 + lane];
    accL = __builtin_amdgcn_mfma_f32_16x16x32_bf16(a, bW, accL, 0, 0, 0);
    accA = __builtin_amdgcn_mfma_f32_16x16x32_bf16(a, bA, accA, 0, 0, 0);
  }
  const int c = nfr * 16 + (lane & 15);
  if (c < CC) {
    const float bf = b_fc[c];
    #pragma unroll
    for (int rr = 0; rr < 4; ++rr) {
      int b = mt * 16 + (lane >> 4) * 4 + rr;
      logits[b * CC + c] = accL[rr] + bf;
      AE[b * CC + c]     = accA[rr];
    }
  }
}

// ---------------------------------------------------------------- softmax + argmax + En2 + Pp (bf16 frag of p)
__global__ __launch_bounds__(256) void softmax_kernel(const float* __restrict__ logits,
                                                      const float* __restrict__ emb,
                                                      float* __restrict__ p,
                                                      short* __restrict__ Pp,
                                                      int* __restrict__ pred,
                                                      float* __restrict__ En2) {
  int b = blockIdx.x, t = threadIdx.x;
  __shared__ float smax[256];
  __shared__ int   sidx[256];
  __shared__ float ssum[256];
  {
    float pe = 0.f;
    for (int k = t; k < DD; k += 256) { float e = emb[b * DD + k]; pe += e * e; }
    #pragma unroll
    for (int o = 1; o < 64; o <<= 1) pe += __shfl_xor(pe, o);
    __shared__ float se[4];
    if ((t & 63) == 0) se[t >> 6] = pe;
    __syncthreads();
    if (t == 0) En2[b] = se[0] + se[1] + se[2] + se[3];
  }
  float m = -3.402823466e38f; int mi = 0;
  for (int c = t; c < CC; c += 256) {
    float v = logits[b * CC + c];
    if (v > m) { m = v; mi = c; }
  }
  smax[t] = m; sidx[t] = mi;
  __syncthreads();
  for (int o = 128; o > 0; o >>= 1) {
    if (t < o) {
      float v2 = smax[t + o]; int i2 = sidx[t + o];
      if (v2 > smax[t] || (v2 == smax[t] && i2 < sidx[t])) { smax[t] = v2; sidx[t] = i2; }
    }
    __syncthreads();
  }
  float M = smax[0];
  if (t == 0) pred[b] = sidx[0];
  float sum = 0.f;
  for (int c = t; c < CC; c += 256) sum += expf(logits[b * CC + c] - M);
  ssum[t] = sum;
  __syncthreads();
  for (int o = 128; o > 0; o >>= 1) {
    if (t < o) ssum[t] += ssum[t + o];
    __syncthreads();
  }
  float S = ssum[0];
  const int mt = b >> 4, blo = b & 15;
  for (int j = t; j < CC; j += 256) {
    float pj = expf(logits[b * CC + j] - M) / S;
    p[b * CC + j] = pj;
    size_t fi = ((size_t)(mt * 32 + (j >> 5)) * 64 + ((j >> 3) & 3) * 16 + blo) * 8 + (j & 7);
    Pp[fi] = (short)f2bf_rne(pj);
  }
  if (t < 24) {     // zero k-pad 1000..1023
    int j = 1000 + t;
    size_t fi = ((size_t)(mt * 32 + (j >> 5)) * 64 + ((j >> 3) & 3) * 16 + blo) * 8 + (j & 7);
    Pp[fi] = 0;
  }
}

// ---------------------------------------------------------------- u = p @ V via MFMA (grid 64 x 4, 1 wave)
__global__ __launch_bounds__(64) void u_kernel(const short* __restrict__ Pp,
                                               const short* __restrict__ Vp,
                                               float* __restrict__ u) {
  const int nfr = blockIdx.x;                  // 0..63
  const int mt  = blockIdx.y;                  // 0..3
  const int lane = threadIdx.x;
  const s16x8* P = (const s16x8*)Pp;
  const s16x8* V = (const s16x8*)Vp;
  f32x4 acc = {};
  for (int ks = 0; ks < 32; ++ks) {
    s16x8 b = V[(nfr * 32 + ks) * 64 + lane];
    acc = __builtin_amdgcn_mfma_f32_16x16x32_bf16(P[(mt * 32 + ks) * 64 + lane], b, acc, 0, 0, 0);
  }
  const int c = nfr * 16 + (lane & 15);
  if (c < CC) {
    #pragma unroll
    for (int rr = 0; rr < 4; ++rr)
      u[(mt * 16 + (lane >> 4) * 4 + rr) * CC + c] = acc[rr];
  }
}

// ---------------------------------------------------------------- scan v3: thread owns 4 j's; loop over c-slice; no reductions
// grid (64, 8): block = (b, c-slice of 125). V[j,c] = V[c,j] (symmetric) -> coalesced uint2 per c.
// partial argmax keys -> part[cz][b*1000+j]; merged in counts.
__global__ __launch_bounds__(256) void scan_kernel(const float* __restrict__ logits,
                                                   const float* __restrict__ u,
                                                   const float* __restrict__ p,
                                                   const float* __restrict__ AE,
                                                   const float* __restrict__ An2,
                                                   const float* __restrict__ En2,
                                                   const unsigned short* __restrict__ Vb,
                                                   unsigned long long* __restrict__ part) {
  const int b = blockIdx.x, cz = blockIdx.y;   // cz < 8
  const int tid = threadIdx.x;
  const int c0 = cz * 125;
  __shared__ __attribute__((aligned(8))) float2 LU[128];
  __shared__ float se[4];

  if (tid < 125) {
    int c = c0 + tid;
    LU[tid] = float2{logits[b * CC + c], u[b * CC + c]};
  }
  // Gn2 = sum_c p*u (fixed-order tree -> identical across all cz blocks)
  float partsum = 0.f;
  {
    int cg = tid * 4;
    if (cg + 3 < CC) {
      float4 p4 = *(const float4*)(p + b * CC + cg);
      float4 u4 = *(const float4*)(u + b * CC + cg);
      partsum = p4.x*u4.x + p4.y*u4.y + p4.z*u4.z + p4.w*u4.w;
    } else {
      #pragma unroll
      for (int i = 0; i < 4; ++i) {
        int c = cg + i;
        if (c < CC) partsum += p[b * CC + c] * u[b * CC + c];
      }
    }
  }
  #pragma unroll
  for (int o = 1; o < 64; o <<= 1) partsum += __shfl_xor(partsum, o);
  if ((tid & 63) == 0) se[tid >> 6] = partsum;
  __syncthreads();
  const float gn2b = se[0] + se[1] + se[2] + se[3];
  const float en2 = En2[b];

  // this thread's 4 j's (threads 250..255 duplicate 249, don't write)
  const int jt = (tid < 250 ? tid : 249) * 4;
  float4 an4 = *(const float4*)(An2 + jt);
  float4 ae4 = *(const float4*)(AE + b * CC + jt);
  float4 uj4 = *(const float4*)(u + b * CC + jt);
  float sj[4], nsj[4];
  {
    float anv[4] = {an4.x, an4.y, an4.z, an4.w};
    float aev[4] = {ae4.x, ae4.y, ae4.z, ae4.w};
    float ujv[4] = {uj4.x, uj4.y, uj4.z, uj4.w};
    #pragma unroll
    for (int k = 0; k < 4; ++k) {
      float vd  = bf2f(Vb[(size_t)(jt + k) * 1024 + jt + k]);
      float zn2 = anv[k] - 2.0f * aev[k] + en2;
      float gn2 = gn2b - 2.0f * ujv[k] + vd;
      sj[k] = (EPSA * sqrtf(zn2)) / sqrtf(gn2);
      nsj[k] = -sj[k];
    }
  }

  float best[4] = {-3.402823466e38f, -3.402823466e38f, -3.402823466e38f, -3.402823466e38f};
  int   bi[4]   = {0, 0, 0, 0};
  const unsigned short* Vcol = Vb + jt;
  #pragma unroll 5
  for (int i = 0; i < 125; ++i) {
    int c = c0 + i;
    float2 lu = LU[i];                                   // broadcast (lane-uniform)
    uint2 vv = *(const uint2*)(Vcol + (size_t)c * 1024); // V[c][jt..jt+3], coalesced
    float v0 = __uint_as_float(vv.x << 16);
    float v1 = __uint_as_float(vv.x & 0xffff0000u);
    float v2 = __uint_as_float(vv.y << 16);
    float v3 = __uint_as_float(vv.y & 0xffff0000u);
    float t0 = fmaf(sj[0], lu.y, lu.x);
    float t1 = fmaf(sj[1], lu.y, lu.x);
    float t2 = fmaf(sj[2], lu.y, lu.x);
    float t3 = fmaf(sj[3], lu.y, lu.x);
    float val0 = fmaf(nsj[0], v0, t0);
    float val1 = fmaf(nsj[1], v1, t1);
    float val2 = fmaf(nsj[2], v2, t2);
    float val3 = fmaf(nsj[3], v3, t3);
    if (val0 > best[0]) { best[0] = val0; bi[0] = c; }   // ascending c + strict > = first max
    if (val1 > best[1]) { best[1] = val1; bi[1] = c; }
    if (val2 > best[2]) { best[2] = val2; bi[2] = c; }
    if (val3 > best[3]) { best[3] = val3; bi[3] = c; }
  }

  if (tid < 250) {
    unsigned long long* dst = part + (size_t)cz * 64000 + b * 1000 + jt;
    #pragma unroll
    for (int k = 0; k < 4; ++k) {
      unsigned ub = __float_as_uint(best[k]);
      ub = (ub & 0x80000000u) ? ~ub : (ub | 0x80000000u);
      dst[k] = ((unsigned long long)ub << 32) |
               (unsigned long long)(0xFFFFFFFFu - (unsigned)bi[k]);   // tie -> smaller c
    }
  }
}

// ---------------------------------------------------------------- counts: merge 8 c-slices + all(counts < 3)
__global__ __launch_bounds__(256) void counts_kernel(const unsigned long long* __restrict__ part,
                                                     const int* __restrict__ pred,
                                                     float* __restrict__ out) {
  int b = blockIdx.x, t = threadIdx.x;
  __shared__ int cnt[CC];
  __shared__ int bad;
  for (int c = t; c < CC; c += 256) cnt[c] = 0;
  if (t == 0) bad = 0;
  __syncthreads();
  if (t == 0) atomicAdd(&cnt[pred[b]], 1);
  const unsigned long long* pr = part + b * 1000;
  for (int j = t; j < CC; j += 256) {
    unsigned long long key = 0;
    #pragma unroll
    for (int cz = 0; cz < 8; ++cz) {
      unsigned long long k2 = pr[(size_t)cz * 64000 + j];
      key = (k2 > key) ? k2 : key;
    }
    int c = (int)(0xFFFFFFFFu - (unsigned)(key & 0xFFFFFFFFull));
    atomicAdd(&cnt[c], 1);
  }
  __syncthreads();
  for (int c = t; c < CC; c += 256) if (cnt[c] >= NSIM) bad = 1;
  __syncthreads();
  if (t == 0) out[b] = bad ? 0.0f : 1.0f;
}

// ---------------------------------------------------------------- launch
extern "C" void kernel_launch(void* const* d_in, const int* in_sizes, int n_in,
                              void* d_out, int out_size, void* d_ws, size_t ws_size,
                              hipStream_t stream) {
  const float* x       = (const float*)d_in[0];
  const float* W_emb   = (const float*)d_in[1];
  const float* b_emb   = (const float*)d_in[2];
  const float* W_fc    = (const float*)d_in[3];
  const float* b_fc    = (const float*)d_in[4];
  const float* anchors = (const float*)d_in[5];
  float* out = (float*)d_out;

  // workspace carve (~14.4 MB), all aligned
  float* emb    = (float*)d_ws;               // 64*768
  float* logits = emb + BB * DD;              // 64*1000
  float* p      = logits + BB * CC;           // 64*1000
  float* u      = p + BB * CC;                // 64*1000
  float* AE     = u + BB * CC;                // 64*1000
  float* An2    = AE + BB * CC;               // 1024
  float* En2    = An2 + 1024;                 // 64
  int*   pred   = (int*)(En2 + 64);           // 64
  unsigned long long* part = (unsigned long long*)(pred + 64);   // 8*64000 u64 (4 MB), 8B-aligned
  short* Bp     = (short*)(part + 8 * 64000); // 786432 shorts
  short* Ap     = Bp + 64 * 24 * 64 * 8;      // 786432
  short* Ip     = Ap + 64 * 24 * 64 * 8;      // 786432
  short* Xp     = Ip + 48 * 32 * 64 * 8;      // 65536
  short* Ep     = Xp + 4 * 32 * 64 * 8;       // 49152
  short* Pp     = Ep + 4 * 24 * 64 * 8;       // 65536
  unsigned short* Vb = (unsigned short*)(Pp + 4 * 32 * 64 * 8);  // 1024*1024
  short* Vp     = (short*)(Vb + 1024 * 1024); // 1048576

  hipLaunchKernelGGL(prep_kernel,    dim3(1434), dim3(256), 0, stream,
                     W_fc, anchors, W_emb, x, Bp, Ap, Ip, Xp, An2);
  hipLaunchKernelGGL(embV_kernel,    dim3(268), dim3(256), 0, stream, Bp, Ip, Xp, b_emb, Vb, emb);
  hipLaunchKernelGGL(packmid_kernel, dim3(536), dim3(256), 0, stream, Vb, emb, Vp, Ep);
  hipLaunchKernelGGL(logitsAE_kernel,dim3(64, 4), dim3(64), 0, stream, Ep, Bp, Ap, b_fc, logits, AE);
  hipLaunchKernelGGL(softmax_kernel, dim3(BB), dim3(256), 0, stream, logits, emb, p, Pp, pred, En2);
  hipLaunchKernelGGL(u_kernel,       dim3(64, 4), dim3(64), 0, stream, Pp, Vp, u);
  hipLaunchKernelGGL(scan_kernel,    dim3(BB, 8), dim3(256), 0, stream,
                     logits, u, p, AE, An2, En2, Vb, part);
  hipLaunchKernelGGL(counts_kernel,  dim3(BB), dim3(256), 0, stream, part, pred, out);
}